// Round 4
// baseline (4740.866 us; speedup 1.0000x reference)
//
#include <hip/hip_runtime.h>

typedef unsigned short u16;
typedef unsigned int u32;
typedef __attribute__((ext_vector_type(8))) short short8;
typedef __attribute__((ext_vector_type(4))) float f32x4;

#define B_  4
#define T_  2048
#define D_  1024
#define H_  8
#define DH_ 128
#define DFF_ 1365
#define DFFP 1408     // padded DFF (1408 = 11*128)
#define NLR 2816      // 2*DFFP

__device__ __forceinline__ u16 f2bf(float f) {
    u32 u = __float_as_uint(f);
    u32 r = (u + 0x7fffu + ((u >> 16) & 1u)) >> 16;
    return (u16)r;
}
__device__ __forceinline__ float bf2f(u16 v) {
    return __uint_as_float(((u32)v) << 16);
}
__device__ __forceinline__ float frcp(float x) { return __builtin_amdgcn_rcpf(x); }

// ---------------------------------------------------------------- LN over x
__global__ void ln_x_kernel(const float* __restrict__ x, const float* __restrict__ g,
                            const float* __restrict__ b, u16* __restrict__ xn) {
    int row = blockIdx.x, tid = threadIdx.x;
    int lane = tid & 63, wv = tid >> 6;
    __shared__ float red[8];
    float4 v = ((const float4*)(x + (size_t)row * D_))[tid];
    float s = v.x + v.y + v.z + v.w;
    float s2 = v.x * v.x + v.y * v.y + v.z * v.z + v.w * v.w;
#pragma unroll
    for (int o = 32; o >= 1; o >>= 1) { s += __shfl_xor(s, o); s2 += __shfl_xor(s2, o); }
    if (lane == 0) { red[wv] = s; red[4 + wv] = s2; }
    __syncthreads();
    s = red[0] + red[1] + red[2] + red[3];
    s2 = red[4] + red[5] + red[6] + red[7];
    float mu = s * (1.f / D_);
    float var = s2 * (1.f / D_) - mu * mu;
    float inv = rsqrtf(var + 1e-5f);
    int c0 = tid * 4;
    ushort4 o4;
    o4.x = f2bf((v.x - mu) * inv * g[c0 + 0] + b[c0 + 0]);
    o4.y = f2bf((v.y - mu) * inv * g[c0 + 1] + b[c0 + 1]);
    o4.z = f2bf((v.z - mu) * inv * g[c0 + 2] + b[c0 + 2]);
    o4.w = f2bf((v.w - mu) * inv * g[c0 + 3] + b[c0 + 3]);
    ((ushort4*)(xn + (size_t)row * D_))[tid] = o4;
}

// ----------------------------------------- fp32 causal conv + bias + swish
// out[m][o] = swish( sum_{din,k} xn[m+k-3][din]*cw[o][din][k] + cb[o] )
#define CONV_DC 32
__global__ __launch_bounds__(256) void conv2_kernel(
    const u16* __restrict__ xn, const float* __restrict__ cw,
    const float* __restrict__ cb, float* __restrict__ xif) {
    const int m0 = blockIdx.y * 32;
    const int n0 = blockIdx.x * 64;
    const int tid = threadIdx.x;
    const int dout = tid & 63, rg = tid >> 6;   // rg 0..3, 8 rows each
    __shared__ float xs[35 * CONV_DC];          // [tile_row][din], tile_row0 = m0-3
    __shared__ float4 ws4[CONV_DC * 65];        // [din][dout], stride 65

    const float4* cw4 = (const float4*)cw;      // cw4[o*1024 + din] = taps[0..3]
    float acc[8];
#pragma unroll
    for (int q = 0; q < 8; ++q) acc[q] = 0.f;
    const int t0 = m0 & (T_ - 1);

    for (int dc = 0; dc < D_; dc += CONV_DC) {
        __syncthreads();
        for (int s = tid; s < 35 * CONV_DC; s += 256) {
            int j = s >> 5, di = s & 31;
            float v = 0.f;
            if (t0 != 0 || j >= 3) v = bf2f(xn[(size_t)(m0 - 3 + j) * D_ + dc + di]);
            xs[j * CONV_DC + di] = v;
        }
#pragma unroll
        for (int it = 0; it < 8; ++it) {
            int s = tid + it * 256;
            int di = s & 31, dq = s >> 5;
            ws4[di * 65 + dq] = cw4[(size_t)(n0 + dq) * 1024 + dc + di];
        }
        __syncthreads();
#pragma unroll 2
        for (int di = 0; di < CONV_DC; ++di) {
            float4 w4 = ws4[di * 65 + dout];
            float xv[11];
#pragma unroll
            for (int u = 0; u < 11; ++u) xv[u] = xs[(rg * 8 + u) * CONV_DC + di];
#pragma unroll
            for (int q = 0; q < 8; ++q)
                acc[q] += xv[q] * w4.x + xv[q + 1] * w4.y + xv[q + 2] * w4.z + xv[q + 3] * w4.w;
        }
    }
    float bias = cb[n0 + dout];
#pragma unroll
    for (int q = 0; q < 8; ++q) {
        int row = m0 + rg * 8 + q;
        float s = acc[q] + bias;
        float sw = s * frcp(1.f + __expf(-s));
        xif[(size_t)row * D_ + n0 + dout] = sw;
    }
}

// ----------------------------------------- fp32 block-diag gate projections
// WGIF[(row*D+gd)*2 + {0:i,1:f}] fp32 ; WGZO[(row*D+gd)*2 + {0:z,1:o}] bf16
__global__ __launch_bounds__(256) void proj2_kernel(
    const u16* __restrict__ xn, const float* __restrict__ xif,
    const float* __restrict__ Wz, const float* __restrict__ Wi,
    const float* __restrict__ Wf, const float* __restrict__ Wo,
    const float* __restrict__ bz, const float* __restrict__ bi,
    const float* __restrict__ bfv, const float* __restrict__ bo,
    float* __restrict__ wgif, u16* __restrict__ wgzo) {
    const int m0 = blockIdx.x * 32;
    const int hd = blockIdx.y;
    const int tid = threadIdx.x;
    const int e = tid & 127, half = tid >> 7;
    __shared__ float xns[32][128];
    __shared__ float xfs[32][128];
    for (int s = tid; s < 32 * 128; s += 256) {
        int r = s >> 7, d = s & 127;
        xns[r][d] = bf2f(xn[(size_t)(m0 + r) * D_ + hd * DH_ + d]);
        xfs[r][d] = xif[(size_t)(m0 + r) * D_ + hd * DH_ + d];
    }
    __syncthreads();
    const float* WA = half ? Wo : Wz;   // xn-sourced gate
    const float* WB = half ? Wf : Wi;   // xif-sourced gate
    float accA[32], accB[32];
#pragma unroll
    for (int r = 0; r < 32; ++r) { accA[r] = 0.f; accB[r] = 0.f; }
    for (int d = 0; d < 128; ++d) {
        float wa = WA[((size_t)hd * DH_ + d) * DH_ + e];
        float wb = WB[((size_t)hd * DH_ + d) * DH_ + e];
#pragma unroll
        for (int r = 0; r < 32; ++r) {
            accA[r] += xns[r][d] * wa;
            accB[r] += xfs[r][d] * wb;
        }
    }
    float ba = half ? bo[hd * DH_ + e] : bz[hd * DH_ + e];
    float bb = half ? bfv[hd * DH_ + e] : bi[hd * DH_ + e];
#pragma unroll
    for (int r = 0; r < 32; ++r) {
        size_t base = ((size_t)(m0 + r) * D_ + hd * DH_ + e) * 2;
        wgif[base + half] = accB[r] + bb;
        wgzo[base + half] = f2bf(accA[r] + ba);
    }
}

// ------------------------------------------------- MLP weight repack (bf16)
__global__ void build_blr(const float* __restrict__ lw, const float* __restrict__ rw,
                          u16* __restrict__ o) {
    int i = blockIdx.x * 256 + threadIdx.x;      // over 2816*1024
    int k = i & 1023, n = i >> 10;
    float v = 0.f;
    if (n < DFF_) v = lw[(size_t)n * D_ + k];
    else if (n >= DFFP && n < DFFP + DFF_) v = rw[(size_t)(n - DFFP) * D_ + k];
    o[i] = f2bf(v);
}
__global__ void build_blast(const float* __restrict__ lw, u16* __restrict__ o) {
    int n = blockIdx.x;                          // 1024 rows
    for (int k = threadIdx.x; k < DFFP; k += 256) {
        float v = (k < DFF_) ? lw[(size_t)n * DFF_ + k] : 0.f;
        o[(size_t)n * DFFP + k] = f2bf(v);
    }
}

// ---------------------------------------------------------------- GEMM (MLP)
// MODE 2=LR(->ZLR bf16) 3=LAST(->fp32 out + bias + skip)
template <int MODE>
__global__ __launch_bounds__(256) void gemm_k(
    const u16* __restrict__ A, const u16* __restrict__ Bg, int K, int lda,
    const float* __restrict__ bias0, const float* __restrict__ bias1,
    const float* __restrict__ add0, u16* __restrict__ o16, float* __restrict__ o32) {
    const int tid = threadIdx.x;
    const int m0 = blockIdx.y * 128;
    const int n0 = blockIdx.x * 128;
    __shared__ u16 As[128][72];
    __shared__ u16 Bs[128][72];

    f32x4 zero4 = {0.f, 0.f, 0.f, 0.f};
    f32x4 acc[4][4];
#pragma unroll
    for (int i = 0; i < 4; ++i)
#pragma unroll
        for (int j = 0; j < 4; ++j) acc[i][j] = zero4;

    const int lane = tid & 63, wv = tid >> 6;
    const int wr = (wv >> 1) * 64, wc = (wv & 1) * 64;
    const int fr = lane & 15, kg = (lane >> 4) * 8;

    for (int kb = 0; kb < K; kb += 64) {
#pragma unroll
        for (int it = 0; it < 4; ++it) {
            int slot = tid + it * 256;
            int r = slot >> 3, ch = slot & 7;
            uint4 va = *(const uint4*)(A + (size_t)(m0 + r) * lda + kb + ch * 8);
            *(uint4*)(&As[r][ch * 8]) = va;
            uint4 vb = *(const uint4*)(Bg + (size_t)(n0 + r) * K + kb + ch * 8);
            *(uint4*)(&Bs[r][ch * 8]) = vb;
        }
        __syncthreads();
#pragma unroll
        for (int kt = 0; kt < 2; ++kt) {
            short8 af[4], bfr[4];
#pragma unroll
            for (int i = 0; i < 4; ++i)
                af[i] = *(const short8*)(&As[wr + i * 16 + fr][kt * 32 + kg]);
#pragma unroll
            for (int i = 0; i < 4; ++i)
                bfr[i] = *(const short8*)(&Bs[wc + i * 16 + fr][kt * 32 + kg]);
#pragma unroll
            for (int mi = 0; mi < 4; ++mi)
#pragma unroll
                for (int ni = 0; ni < 4; ++ni)
                    acc[mi][ni] = __builtin_amdgcn_mfma_f32_16x16x32_bf16(
                        af[mi], bfr[ni], acc[mi][ni], 0, 0, 0);
        }
        __syncthreads();
    }
#pragma unroll
    for (int mi = 0; mi < 4; ++mi) {
#pragma unroll
        for (int ni = 0; ni < 4; ++ni) {
#pragma unroll
            for (int r = 0; r < 4; ++r) {
                int row = m0 + wr + mi * 16 + (lane >> 4) * 4 + r;
                int col = n0 + wc + ni * 16 + fr;
                float v = acc[mi][ni][r];
                if constexpr (MODE == 2) {
                    float bv = 0.f;
                    if (col < DFF_) bv = bias0[col];
                    else if (col >= DFFP && col < DFFP + DFF_) bv = bias1[col - DFFP];
                    o16[(size_t)row * NLR + col] = f2bf(v + bv);
                } else {
                    float r0 = v + bias0[col] + add0[(size_t)row * D_ + col];
                    o32[(size_t)row * D_ + col] = r0;
                }
            }
        }
    }
}

// ---------------------------------------------------------------- scan
// WGIF fp32 (i,f), WGZO bf16 (z,o). h hi/lo bf16; R hi/lo bf16 (3 MFMA chains).
__global__ __launch_bounds__(512) void scan_kernel(
    const float* __restrict__ wgif, const u16* __restrict__ wgzo,
    const float* __restrict__ Rz, const float* __restrict__ Ri,
    const float* __restrict__ Rf, const float* __restrict__ Ro,
    u16* __restrict__ hseq, float* __restrict__ st_out) {
    const int head = blockIdx.x;
    const int tid = threadIdx.x;
    const int lane = tid & 63, wv = tid >> 6;

    __shared__ u16 hi_lds[16][136];
    __shared__ u16 lo_lds[16][136];
    __shared__ float z_lds[4][4][128];

    for (int i = tid; i < 16 * 136; i += 512) {
        ((u16*)hi_lds)[i] = 0;
        ((u16*)lo_lds)[i] = 0;
    }

    // preload R fragments hi/lo (B operand)
    short8 bfh[4][4], bfl[4][4];
    {
        const float* Rp[4] = {Rz, Ri, Rf, Ro};
        const int g = wv >> 1;
        const float* R = Rp[g] + (size_t)head * DH_ * DH_;
        const int csub = (wv & 1) * 64;
#pragma unroll
        for (int nt = 0; nt < 4; ++nt) {
            int e = csub + nt * 16 + (lane & 15);
#pragma unroll
            for (int kt = 0; kt < 4; ++kt) {
                short8 vh, vl;
#pragma unroll
                for (int j = 0; j < 8; ++j) {
                    int k = kt * 32 + ((lane >> 4) << 3) + j;
                    float rv = R[(size_t)k * DH_ + e];
                    u16 hi = f2bf(rv);
                    u16 lo = f2bf(rv - bf2f(hi));
                    vh[j] = (short)hi;
                    vl[j] = (short)lo;
                }
                bfh[nt][kt] = vh;
                bfl[nt][kt] = vl;
            }
        }
    }

    const int b = tid >> 7;
    const int dq = tid & 127;
    size_t idx = (size_t)b * T_ * D_ + (size_t)head * DH_ + dq;
    float c_s = 0.f, n_s = 0.f, m_s = 0.f, h_s = 0.f;

    float2 pif = *(const float2*)(wgif + idx * 2);
    u32 pzo = *(const u32*)(wgzo + idx * 2);

    const int fr = lane & 15, kg = (lane >> 4) * 8;
    const int gsel = wv >> 1, cbase = (wv & 1) * 64;

    __syncthreads();

    for (int t = 0; t < T_; ++t) {
        short8 ah[4], al[4];
#pragma unroll
        for (int kt = 0; kt < 4; ++kt) {
            ah[kt] = *(const short8*)(&hi_lds[fr][kt * 32 + kg]);
            al[kt] = *(const short8*)(&lo_lds[fr][kt * 32 + kg]);
        }
#pragma unroll
        for (int nt = 0; nt < 4; ++nt) {
            f32x4 a = {0.f, 0.f, 0.f, 0.f};
#pragma unroll
            for (int kt = 0; kt < 4; ++kt)
                a = __builtin_amdgcn_mfma_f32_16x16x32_bf16(ah[kt], bfh[nt][kt], a, 0, 0, 0);
#pragma unroll
            for (int kt = 0; kt < 4; ++kt)
                a = __builtin_amdgcn_mfma_f32_16x16x32_bf16(al[kt], bfh[nt][kt], a, 0, 0, 0);
#pragma unroll
            for (int kt = 0; kt < 4; ++kt)
                a = __builtin_amdgcn_mfma_f32_16x16x32_bf16(ah[kt], bfl[nt][kt], a, 0, 0, 0);
            if (lane < 16) {
#pragma unroll
                for (int r = 0; r < 4; ++r)
                    z_lds[gsel][r][cbase + nt * 16 + lane] = a[r];
            }
        }
        __syncthreads();

        float vi = pif.x, vf = pif.y;
        float vz = bf2f((u16)(pzo & 0xffffu)), vo = bf2f((u16)(pzo >> 16));
        if (t < T_ - 1) {
            pif = *(const float2*)(wgif + (idx + D_) * 2);
            pzo = *(const u32*)(wgzo + (idx + D_) * 2);
        }
        float zb = vz + z_lds[0][b][dq];
        float ib = vi + z_lds[1][b][dq];
        float fb = vf + z_lds[2][b][dq];
        float ob = vo + z_lds[3][b][dq];
        float z = 1.f - 2.f * frcp(__expf(2.f * zb) + 1.f);
        float o = frcp(1.f + __expf(-ob));
        float mn = fmaxf(fb + m_s, ib);
        float ii = __expf(ib - mn);
        float ff = __expf(fb + m_s - mn);
        c_s = ff * c_s + ii * z;
        n_s = ff * n_s + ii;
        m_s = mn;
        h_s = o * c_s * frcp(fmaxf(fabsf(n_s), 1e-8f));
        u16 hb = f2bf(h_s);
        u16 lb = f2bf(h_s - bf2f(hb));
        hi_lds[b][dq] = hb;
        lo_lds[b][dq] = lb;
        hseq[idx] = hb;
        idx += D_;
        __syncthreads();
    }

    int pos = b * D_ + head * DH_ + dq;
    st_out[pos] = h_s;
    st_out[4096 + pos] = c_s;
    st_out[8192 + pos] = n_s;
    st_out[12288 + pos] = m_s;
}

// --------------------------------------------- GN + skip + LN (post) per row
__global__ void post_kernel(const u16* __restrict__ hseq, const float* __restrict__ x,
                            const float* __restrict__ gn_g, const float* __restrict__ gn_b,
                            const float* __restrict__ ln_g, const float* __restrict__ ln_b,
                            float* __restrict__ hskip, u16* __restrict__ hn) {
    int row = blockIdx.x, tid = threadIdx.x;
    int lane = tid & 63, wv = tid >> 6;
    __shared__ float red[8];
    ushort4 hv = ((const ushort4*)(hseq + (size_t)row * D_))[tid];
    float h0 = bf2f(hv.x), h1 = bf2f(hv.y), h2 = bf2f(hv.z), h3 = bf2f(hv.w);
    float s = h0 + h1 + h2 + h3;
    float s2 = h0 * h0 + h1 * h1 + h2 * h2 + h3 * h3;
#pragma unroll
    for (int o = 32; o >= 1; o >>= 1) { s += __shfl_xor(s, o); s2 += __shfl_xor(s2, o); }
    if (lane == 0) { red[wv] = s; red[4 + wv] = s2; }
    __syncthreads();
    s = red[0] + red[1] + red[2] + red[3];
    s2 = red[4] + red[5] + red[6] + red[7];
    float mu = s * (1.f / D_);
    float var = s2 * (1.f / D_) - mu * mu;
    float inv = rsqrtf(var + 1e-5f);
    float4 xv = ((const float4*)(x + (size_t)row * D_))[tid];
    int c0 = tid * 4;
    float k0 = (h0 - mu) * inv * gn_g[c0 + 0] + gn_b[c0 + 0] + xv.x;
    float k1 = (h1 - mu) * inv * gn_g[c0 + 1] + gn_b[c0 + 1] + xv.y;
    float k2 = (h2 - mu) * inv * gn_g[c0 + 2] + gn_b[c0 + 2] + xv.z;
    float k3 = (h3 - mu) * inv * gn_g[c0 + 3] + gn_b[c0 + 3] + xv.w;
    ((float4*)(hskip + (size_t)row * D_))[tid] = make_float4(k0, k1, k2, k3);
    float t1 = k0 + k1 + k2 + k3;
    float t2 = k0 * k0 + k1 * k1 + k2 * k2 + k3 * k3;
#pragma unroll
    for (int o = 32; o >= 1; o >>= 1) { t1 += __shfl_xor(t1, o); t2 += __shfl_xor(t2, o); }
    __syncthreads();
    if (lane == 0) { red[wv] = t1; red[4 + wv] = t2; }
    __syncthreads();
    t1 = red[0] + red[1] + red[2] + red[3];
    t2 = red[4] + red[5] + red[6] + red[7];
    float mu2 = t1 * (1.f / D_);
    float var2 = t2 * (1.f / D_) - mu2 * mu2;
    float inv2 = rsqrtf(var2 + 1e-5f);
    ushort4 o4;
    o4.x = f2bf((k0 - mu2) * inv2 * ln_g[c0 + 0] + ln_b[c0 + 0]);
    o4.y = f2bf((k1 - mu2) * inv2 * ln_g[c0 + 1] + ln_b[c0 + 1]);
    o4.z = f2bf((k2 - mu2) * inv2 * ln_g[c0 + 2] + ln_b[c0 + 2]);
    o4.w = f2bf((k3 - mu2) * inv2 * ln_g[c0 + 3] + ln_b[c0 + 3]);
    ((ushort4*)(hn + (size_t)row * D_))[tid] = o4;
}

// ---------------------------------------------------------------- GLU pointwise
__global__ void glu_kernel(const u16* __restrict__ zlr, u16* __restrict__ glu) {
    int row = blockIdx.x;
    for (int n = threadIdx.x; n < DFFP; n += 256) {
        float g = 0.f;
        if (n < DFF_) {
            float zl = bf2f(zlr[(size_t)row * NLR + n]);
            float zr = bf2f(zlr[(size_t)row * NLR + DFFP + n]);
            float ge = 0.5f * zr * (1.f + erff(zr * 0.70710678118654752f));
            g = zl * ge;
        }
        glu[(size_t)row * DFFP + n] = f2bf(g);
    }
}

// ---------------------------------------------------------------- launcher
extern "C" void kernel_launch(void* const* d_in, const int* in_sizes, int n_in,
                              void* d_out, int out_size, void* d_ws, size_t ws_size,
                              hipStream_t stream) {
    const float* x      = (const float*)d_in[0];
    const float* Wz     = (const float*)d_in[1];
    const float* Wi     = (const float*)d_in[2];
    const float* Wf     = (const float*)d_in[3];
    const float* Wo     = (const float*)d_in[4];
    const float* bz     = (const float*)d_in[5];
    const float* bi     = (const float*)d_in[6];
    const float* bfb    = (const float*)d_in[7];
    const float* bo     = (const float*)d_in[8];
    const float* Rz     = (const float*)d_in[9];
    const float* Ri     = (const float*)d_in[10];
    const float* Rf     = (const float*)d_in[11];
    const float* Ro     = (const float*)d_in[12];
    const float* conv_w = (const float*)d_in[13];
    const float* conv_b = (const float*)d_in[14];
    const float* ln_g   = (const float*)d_in[15];
    const float* ln_b   = (const float*)d_in[16];
    const float* gn_g   = (const float*)d_in[17];
    const float* gn_b   = (const float*)d_in[18];
    const float* left_w = (const float*)d_in[19];
    const float* left_b = (const float*)d_in[20];
    const float* right_w= (const float*)d_in[21];
    const float* right_b= (const float*)d_in[22];
    const float* last_w = (const float*)d_in[23];
    const float* last_b = (const float*)d_in[24];

    char* ws = (char*)d_ws;
    u16*  BLR   = (u16*)(ws);                     // [2816][1024] bf16
    u16*  BLAST = (u16*)(ws + 5767168);           // [1024][1408] bf16
    u16*  XN    = (u16*)(ws + 8650752);           // [8192][1024] bf16
    float* XIF32= (float*)(ws + 25427968);        // [8192][1024] fp32
    float* WGIF = (float*)(ws + 58982400);        // [8192][1024][2] fp32 (i,f)
    u16*  WGZO  = (u16*)(ws + 126091264);         // [8192][1024][2] bf16 (z,o) -> ends 159,645,696
    // time-disjoint aliases:
    u16*  HSEQ  = (u16*)(ws + 8650752);           // over XN (dead after proj2)
    float* HSKIP= (float*)(ws + 25427968);        // over XIF32 (dead after proj2)
    u16*  HN    = (u16*)(ws + 58982400);          // over WGIF[0,16MB) (dead after scan)
    u16*  ZLR   = (u16*)(ws + 75759616);          // over WGIF[16,60MB)
    u16*  GLU   = (u16*)(ws + 126091264);         // over WGZO (dead after scan)

    float* out = (float*)d_out;
    float* st_out = out + (size_t)B_ * T_ * D_;

    const int M = B_ * T_;

    ln_x_kernel<<<M, 256, 0, stream>>>(x, ln_g, ln_b, XN);
    conv2_kernel<<<dim3(16, 256), 256, 0, stream>>>(XN, conv_w, conv_b, XIF32);
    proj2_kernel<<<dim3(256, 8), 256, 0, stream>>>(XN, XIF32, Wz, Wi, Wf, Wo,
                                                   bz, bi, bfb, bo, WGIF, WGZO);
    build_blr<<<11264, 256, 0, stream>>>(left_w, right_w, BLR);
    build_blast<<<1024, 256, 0, stream>>>(last_w, BLAST);

    scan_kernel<<<8, 512, 0, stream>>>(WGIF, WGZO, Rz, Ri, Rf, Ro, HSEQ, st_out);
    post_kernel<<<M, 256, 0, stream>>>(HSEQ, x, gn_g, gn_b, ln_g, ln_b, HSKIP, HN);
    gemm_k<2><<<dim3(22, 64), 256, 0, stream>>>(HN, BLR, 1024, 1024, left_b, right_b,
                                                nullptr, ZLR, nullptr);
    glu_kernel<<<M, 256, 0, stream>>>(ZLR, GLU);
    gemm_k<3><<<dim3(8, 64), 256, 0, stream>>>(GLU, BLAST, DFFP, DFFP, last_b, nullptr,
                                               HSKIP, nullptr, out);
}

// Round 5
// 4034.150 us; speedup vs baseline: 1.1752x; 1.1752x over previous
//
#include <hip/hip_runtime.h>

typedef unsigned short u16;
typedef unsigned int u32;
typedef __attribute__((ext_vector_type(8))) short short8;
typedef __attribute__((ext_vector_type(4))) float f32x4;

#define B_  4
#define T_  2048
#define D_  1024
#define H_  8
#define DH_ 128
#define DFF_ 1365
#define DFFP 1408     // padded DFF (1408 = 11*128)
#define NLR 2816      // 2*DFFP

__device__ __forceinline__ u16 f2bf(float f) {
    u32 u = __float_as_uint(f);
    u32 r = (u + 0x7fffu + ((u >> 16) & 1u)) >> 16;
    return (u16)r;
}
__device__ __forceinline__ float bf2f(u16 v) {
    return __uint_as_float(((u32)v) << 16);
}
__device__ __forceinline__ float frcp(float x) { return __builtin_amdgcn_rcpf(x); }

// ---------------------------------------------------------------- LN over x
__global__ void ln_x_kernel(const float* __restrict__ x, const float* __restrict__ g,
                            const float* __restrict__ b, u16* __restrict__ xn) {
    int row = blockIdx.x, tid = threadIdx.x;
    int lane = tid & 63, wv = tid >> 6;
    __shared__ float red[8];
    float4 v = ((const float4*)(x + (size_t)row * D_))[tid];
    float s = v.x + v.y + v.z + v.w;
    float s2 = v.x * v.x + v.y * v.y + v.z * v.z + v.w * v.w;
#pragma unroll
    for (int o = 32; o >= 1; o >>= 1) { s += __shfl_xor(s, o); s2 += __shfl_xor(s2, o); }
    if (lane == 0) { red[wv] = s; red[4 + wv] = s2; }
    __syncthreads();
    s = red[0] + red[1] + red[2] + red[3];
    s2 = red[4] + red[5] + red[6] + red[7];
    float mu = s * (1.f / D_);
    float var = s2 * (1.f / D_) - mu * mu;
    float inv = rsqrtf(var + 1e-5f);
    int c0 = tid * 4;
    ushort4 o4;
    o4.x = f2bf((v.x - mu) * inv * g[c0 + 0] + b[c0 + 0]);
    o4.y = f2bf((v.y - mu) * inv * g[c0 + 1] + b[c0 + 1]);
    o4.z = f2bf((v.z - mu) * inv * g[c0 + 2] + b[c0 + 2]);
    o4.w = f2bf((v.w - mu) * inv * g[c0 + 3] + b[c0 + 3]);
    ((ushort4*)(xn + (size_t)row * D_))[tid] = o4;
}

// -------------------------------------- conv weight repack, hi/lo bf16 split
// kk = ktap*1024 + din (tap-major virtual K); BCH/BCL [dout][kk]
__global__ void build_bconv2(const float* __restrict__ cw, u16* __restrict__ oh,
                             u16* __restrict__ ol) {
    int i = blockIdx.x * 256 + threadIdx.x;      // over 1024*4096
    int din = i & 1023, kt = (i >> 10) & 3, dout = i >> 12;
    float v = cw[((size_t)dout * D_ + din) * 4 + kt];
    u16 hi = f2bf(v);
    oh[i] = hi;
    ol[i] = f2bf(v - bf2f(hi));
}

// ----------------------------------------- fp32 block-diag gate projections
// WGIF[(row*D+gd)*2 + {0:i,1:f}] fp32 ; WGZO[(row*D+gd)*2 + {0:z,1:o}] bf16
__global__ __launch_bounds__(256) void proj2_kernel(
    const u16* __restrict__ xn, const float* __restrict__ xif,
    const float* __restrict__ Wz, const float* __restrict__ Wi,
    const float* __restrict__ Wf, const float* __restrict__ Wo,
    const float* __restrict__ bz, const float* __restrict__ bi,
    const float* __restrict__ bfv, const float* __restrict__ bo,
    float* __restrict__ wgif, u16* __restrict__ wgzo) {
    const int m0 = blockIdx.x * 32;
    const int hd = blockIdx.y;
    const int tid = threadIdx.x;
    const int e = tid & 127, half = tid >> 7;
    __shared__ float xns[32][128];
    __shared__ float xfs[32][128];
    for (int s = tid; s < 32 * 128; s += 256) {
        int r = s >> 7, d = s & 127;
        xns[r][d] = bf2f(xn[(size_t)(m0 + r) * D_ + hd * DH_ + d]);
        xfs[r][d] = xif[(size_t)(m0 + r) * D_ + hd * DH_ + d];
    }
    __syncthreads();
    const float* WA = half ? Wo : Wz;   // xn-sourced gate
    const float* WB = half ? Wf : Wi;   // xif-sourced gate
    float accA[32], accB[32];
#pragma unroll
    for (int r = 0; r < 32; ++r) { accA[r] = 0.f; accB[r] = 0.f; }
    for (int d = 0; d < 128; ++d) {
        float wa = WA[((size_t)hd * DH_ + d) * DH_ + e];
        float wb = WB[((size_t)hd * DH_ + d) * DH_ + e];
#pragma unroll
        for (int r = 0; r < 32; ++r) {
            accA[r] += xns[r][d] * wa;
            accB[r] += xfs[r][d] * wb;
        }
    }
    float ba = half ? bo[hd * DH_ + e] : bz[hd * DH_ + e];
    float bb = half ? bfv[hd * DH_ + e] : bi[hd * DH_ + e];
#pragma unroll
    for (int r = 0; r < 32; ++r) {
        size_t base = ((size_t)(m0 + r) * D_ + hd * DH_ + e) * 2;
        wgif[base + half] = accB[r] + bb;
        wgzo[base + half] = f2bf(accA[r] + ba);
    }
}

// ------------------------------------------------- MLP weight repack (bf16)
__global__ void build_blr(const float* __restrict__ lw, const float* __restrict__ rw,
                          u16* __restrict__ o) {
    int i = blockIdx.x * 256 + threadIdx.x;      // over 2816*1024
    int k = i & 1023, n = i >> 10;
    float v = 0.f;
    if (n < DFF_) v = lw[(size_t)n * D_ + k];
    else if (n >= DFFP && n < DFFP + DFF_) v = rw[(size_t)(n - DFFP) * D_ + k];
    o[i] = f2bf(v);
}
__global__ void build_blast(const float* __restrict__ lw, u16* __restrict__ o) {
    int n = blockIdx.x;                          // 1024 rows
    for (int k = threadIdx.x; k < DFFP; k += 256) {
        float v = (k < DFF_) ? lw[(size_t)n * DFF_ + k] : 0.f;
        o[(size_t)n * DFFP + k] = f2bf(v);
    }
}

// ---------------------------------------------------------------- GEMM
// MODE 0=CONV (virtual tap-major K=4096, B hi/lo, ->swish-> fp32 XIF)
// MODE 2=LR(->ZLR bf16) 3=LAST(->fp32 out + bias + skip)
template <int MODE>
__global__ __launch_bounds__(256) void gemm_k(
    const u16* __restrict__ A, const u16* __restrict__ Bg, const u16* __restrict__ Bg2,
    int K, int lda,
    const float* __restrict__ bias0, const float* __restrict__ bias1,
    const float* __restrict__ add0, u16* __restrict__ o16, float* __restrict__ o32) {
    const int tid = threadIdx.x;
    const int m0 = blockIdx.y * 128;
    const int n0 = blockIdx.x * 128;
    __shared__ u16 As[128][72];
    __shared__ u16 Bs[128][72];
    __shared__ u16 Bs2[(MODE == 0) ? 128 : 1][72];

    f32x4 zero4 = {0.f, 0.f, 0.f, 0.f};
    f32x4 acc[4][4];
#pragma unroll
    for (int i = 0; i < 4; ++i)
#pragma unroll
        for (int j = 0; j < 4; ++j) acc[i][j] = zero4;

    const int lane = tid & 63, wv = tid >> 6;
    const int wr = (wv >> 1) * 64, wc = (wv & 1) * 64;
    const int fr = lane & 15, kg = (lane >> 4) * 8;

    for (int kb = 0; kb < K; kb += 64) {
#pragma unroll
        for (int it = 0; it < 4; ++it) {
            int slot = tid + it * 256;
            int r = slot >> 3, ch = slot & 7;
            uint4 va;
            if constexpr (MODE == 0) {
                int kk = kb + ch * 8;
                int ktap = kk >> 10, din = kk & 1023;
                int m = m0 + r;
                int t = m & (T_ - 1);
                if (t + ktap - 3 >= 0)
                    va = *(const uint4*)(A + (size_t)(m + ktap - 3) * D_ + din);
                else
                    va = make_uint4(0u, 0u, 0u, 0u);
            } else {
                va = *(const uint4*)(A + (size_t)(m0 + r) * lda + kb + ch * 8);
            }
            *(uint4*)(&As[r][ch * 8]) = va;
            uint4 vb = *(const uint4*)(Bg + (size_t)(n0 + r) * K + kb + ch * 8);
            *(uint4*)(&Bs[r][ch * 8]) = vb;
            if constexpr (MODE == 0) {
                uint4 vc = *(const uint4*)(Bg2 + (size_t)(n0 + r) * K + kb + ch * 8);
                *(uint4*)(&Bs2[r][ch * 8]) = vc;
            }
        }
        __syncthreads();
#pragma unroll
        for (int kt = 0; kt < 2; ++kt) {
            short8 af[4], bfr[4];
#pragma unroll
            for (int i = 0; i < 4; ++i)
                af[i] = *(const short8*)(&As[wr + i * 16 + fr][kt * 32 + kg]);
#pragma unroll
            for (int i = 0; i < 4; ++i)
                bfr[i] = *(const short8*)(&Bs[wc + i * 16 + fr][kt * 32 + kg]);
#pragma unroll
            for (int mi = 0; mi < 4; ++mi)
#pragma unroll
                for (int ni = 0; ni < 4; ++ni)
                    acc[mi][ni] = __builtin_amdgcn_mfma_f32_16x16x32_bf16(
                        af[mi], bfr[ni], acc[mi][ni], 0, 0, 0);
            if constexpr (MODE == 0) {
                short8 bl[4];
#pragma unroll
                for (int i = 0; i < 4; ++i)
                    bl[i] = *(const short8*)(&Bs2[wc + i * 16 + fr][kt * 32 + kg]);
#pragma unroll
                for (int mi = 0; mi < 4; ++mi)
#pragma unroll
                    for (int ni = 0; ni < 4; ++ni)
                        acc[mi][ni] = __builtin_amdgcn_mfma_f32_16x16x32_bf16(
                            af[mi], bl[ni], acc[mi][ni], 0, 0, 0);
            }
        }
        __syncthreads();
    }
#pragma unroll
    for (int mi = 0; mi < 4; ++mi) {
#pragma unroll
        for (int ni = 0; ni < 4; ++ni) {
#pragma unroll
            for (int r = 0; r < 4; ++r) {
                int row = m0 + wr + mi * 16 + (lane >> 4) * 4 + r;
                int col = n0 + wc + ni * 16 + fr;
                float v = acc[mi][ni][r];
                if constexpr (MODE == 0) {
                    float s = v + bias0[col];
                    float sw = s * frcp(1.f + __expf(-s));
                    o32[(size_t)row * D_ + col] = sw;
                } else if constexpr (MODE == 2) {
                    float bv = 0.f;
                    if (col < DFF_) bv = bias0[col];
                    else if (col >= DFFP && col < DFFP + DFF_) bv = bias1[col - DFFP];
                    o16[(size_t)row * NLR + col] = f2bf(v + bv);
                } else {
                    float r0 = v + bias0[col] + add0[(size_t)row * D_ + col];
                    o32[(size_t)row * D_ + col] = r0;
                }
            }
        }
    }
}

// ---------------------------------------------------------------- scan (v3)
// Wave wv owns dq slice [wv*16,(wv+1)*16), ALL 4 gates (g = MFMA N-tile).
// C/D layout puts batches 0-3 in regs 0-3 of lanes 0-15 -> pointwise in-wave.
// h double-buffered by parity; ONE raw s_barrier per step (lgkmcnt-only drain,
// so the hseq global store latency stays off the critical path).
__global__ __launch_bounds__(512) void scan3_kernel(
    const float* __restrict__ wgif, const u16* __restrict__ wgzo,
    const float* __restrict__ Rz, const float* __restrict__ Ri,
    const float* __restrict__ Rf, const float* __restrict__ Ro,
    u16* __restrict__ hseq, float* __restrict__ st_out) {
    const int head = blockIdx.x;
    const int tid = threadIdx.x;
    const int lane = tid & 63, wv = tid >> 6;

    __shared__ u16 hbuf[2][2][16][136];   // [parity][hi/lo][row(batch)][dq]

    for (int i = tid; i < 2 * 2 * 16 * 136; i += 512) ((u16*)hbuf)[i] = 0;

    // R fragments hi/lo (B operand): gate g, col e = wv*16 + (lane&15)
    short8 bfh[4][4], bfl[4][4];
    {
        const float* Rp[4] = {Rz, Ri, Rf, Ro};
        const int e = wv * 16 + (lane & 15);
#pragma unroll
        for (int g = 0; g < 4; ++g) {
            const float* R = Rp[g] + (size_t)head * DH_ * DH_;
#pragma unroll
            for (int kt = 0; kt < 4; ++kt) {
                short8 vh, vl;
#pragma unroll
                for (int j = 0; j < 8; ++j) {
                    int k = kt * 32 + ((lane >> 4) << 3) + j;
                    float rv = R[(size_t)k * DH_ + e];
                    u16 hi = f2bf(rv);
                    vh[j] = (short)hi;
                    vl[j] = (short)f2bf(rv - bf2f(hi));
                }
                bfh[g][kt] = vh;
                bfl[g][kt] = vl;
            }
        }
    }

    const int dq = wv * 16 + (lane & 15);
    const bool act = (lane < 16);
    const int fr = lane & 15, kg = (lane >> 4) * 8;

    float c_s[4], n_s[4], m_s[4], h_s[4];
#pragma unroll
    for (int b = 0; b < 4; ++b) { c_s[b] = 0.f; n_s[b] = 0.f; m_s[b] = 0.f; h_s[b] = 0.f; }

    float2 pif[4]; u32 pzo[4];
    if (act) {
#pragma unroll
        for (int b = 0; b < 4; ++b) {
            size_t ix = ((size_t)b * T_) * D_ + (size_t)head * DH_ + dq;
            pif[b] = *(const float2*)(wgif + ix * 2);
            pzo[b] = *(const u32*)(wgzo + ix * 2);
        }
    }
    __syncthreads();

    for (int t = 0; t < T_; ++t) {
        const int p = t & 1, q = p ^ 1;
        short8 ah[4], al[4];
#pragma unroll
        for (int kt = 0; kt < 4; ++kt) {
            ah[kt] = *(const short8*)(&hbuf[p][0][fr][kt * 32 + kg]);
            al[kt] = *(const short8*)(&hbuf[p][1][fr][kt * 32 + kg]);
        }
        // prefetch next step's gate inputs (independent of h)
        float2 nif[4]; u32 nzo[4];
        if (t < T_ - 1 && act) {
#pragma unroll
            for (int b = 0; b < 4; ++b) {
                size_t ix = ((size_t)b * T_ + t + 1) * D_ + (size_t)head * DH_ + dq;
                nif[b] = *(const float2*)(wgif + ix * 2);
                nzo[b] = *(const u32*)(wgzo + ix * 2);
            }
        }
        f32x4 az = {0.f, 0.f, 0.f, 0.f}, ai = az, af2 = az, ao = az;
#pragma unroll
        for (int kt = 0; kt < 4; ++kt) {
            az  = __builtin_amdgcn_mfma_f32_16x16x32_bf16(ah[kt], bfh[0][kt], az, 0, 0, 0);
            ai  = __builtin_amdgcn_mfma_f32_16x16x32_bf16(ah[kt], bfh[1][kt], ai, 0, 0, 0);
            af2 = __builtin_amdgcn_mfma_f32_16x16x32_bf16(ah[kt], bfh[2][kt], af2, 0, 0, 0);
            ao  = __builtin_amdgcn_mfma_f32_16x16x32_bf16(ah[kt], bfh[3][kt], ao, 0, 0, 0);
        }
#pragma unroll
        for (int kt = 0; kt < 4; ++kt) {
            az  = __builtin_amdgcn_mfma_f32_16x16x32_bf16(al[kt], bfh[0][kt], az, 0, 0, 0);
            ai  = __builtin_amdgcn_mfma_f32_16x16x32_bf16(al[kt], bfh[1][kt], ai, 0, 0, 0);
            af2 = __builtin_amdgcn_mfma_f32_16x16x32_bf16(al[kt], bfh[2][kt], af2, 0, 0, 0);
            ao  = __builtin_amdgcn_mfma_f32_16x16x32_bf16(al[kt], bfh[3][kt], ao, 0, 0, 0);
        }
#pragma unroll
        for (int kt = 0; kt < 4; ++kt) {
            az  = __builtin_amdgcn_mfma_f32_16x16x32_bf16(ah[kt], bfl[0][kt], az, 0, 0, 0);
            ai  = __builtin_amdgcn_mfma_f32_16x16x32_bf16(ah[kt], bfl[1][kt], ai, 0, 0, 0);
            af2 = __builtin_amdgcn_mfma_f32_16x16x32_bf16(ah[kt], bfl[2][kt], af2, 0, 0, 0);
            ao  = __builtin_amdgcn_mfma_f32_16x16x32_bf16(ah[kt], bfl[3][kt], ao, 0, 0, 0);
        }
        if (act) {
#pragma unroll
            for (int b = 0; b < 4; ++b) {
                float zb = bf2f((u16)(pzo[b] & 0xffffu)) + az[b];
                float ib = pif[b].x + ai[b];
                float fb = pif[b].y + af2[b];
                float ob = bf2f((u16)(pzo[b] >> 16)) + ao[b];
                float z = 1.f - 2.f * frcp(__expf(2.f * zb) + 1.f);   // tanh
                float o = frcp(1.f + __expf(-ob));                    // sigmoid
                float mn = fmaxf(fb + m_s[b], ib);
                float ii = __expf(ib - mn);
                float ff = __expf(fb + m_s[b] - mn);
                c_s[b] = ff * c_s[b] + ii * z;
                n_s[b] = ff * n_s[b] + ii;
                m_s[b] = mn;
                float hv = o * c_s[b] * frcp(fmaxf(fabsf(n_s[b]), 1e-8f));
                h_s[b] = hv;
                u16 hb = f2bf(hv);
                hbuf[q][0][b][dq] = hb;
                hbuf[q][1][b][dq] = f2bf(hv - bf2f(hb));
                hseq[((size_t)b * T_ + t) * D_ + (size_t)head * DH_ + dq] = hb;
            }
#pragma unroll
            for (int b = 0; b < 4; ++b) { pif[b] = nif[b]; pzo[b] = nzo[b]; }
        }
        // drain LDS writes only (NOT vmcnt: hseq stores + prefetch stay in flight)
        asm volatile("s_waitcnt lgkmcnt(0)\n\ts_barrier" ::: "memory");
    }

    if (act) {
#pragma unroll
        for (int b = 0; b < 4; ++b) {
            int pos = b * D_ + head * DH_ + dq;
            st_out[pos] = h_s[b];
            st_out[4096 + pos] = c_s[b];
            st_out[8192 + pos] = n_s[b];
            st_out[12288 + pos] = m_s[b];
        }
    }
}

// --------------------------------------------- GN + skip + LN (post) per row
__global__ void post_kernel(const u16* __restrict__ hseq, const float* __restrict__ x,
                            const float* __restrict__ gn_g, const float* __restrict__ gn_b,
                            const float* __restrict__ ln_g, const float* __restrict__ ln_b,
                            float* __restrict__ hskip, u16* __restrict__ hn) {
    int row = blockIdx.x, tid = threadIdx.x;
    int lane = tid & 63, wv = tid >> 6;
    __shared__ float red[8];
    ushort4 hv = ((const ushort4*)(hseq + (size_t)row * D_))[tid];
    float h0 = bf2f(hv.x), h1 = bf2f(hv.y), h2 = bf2f(hv.z), h3 = bf2f(hv.w);
    float s = h0 + h1 + h2 + h3;
    float s2 = h0 * h0 + h1 * h1 + h2 * h2 + h3 * h3;
#pragma unroll
    for (int o = 32; o >= 1; o >>= 1) { s += __shfl_xor(s, o); s2 += __shfl_xor(s2, o); }
    if (lane == 0) { red[wv] = s; red[4 + wv] = s2; }
    __syncthreads();
    s = red[0] + red[1] + red[2] + red[3];
    s2 = red[4] + red[5] + red[6] + red[7];
    float mu = s * (1.f / D_);
    float var = s2 * (1.f / D_) - mu * mu;
    float inv = rsqrtf(var + 1e-5f);
    float4 xv = ((const float4*)(x + (size_t)row * D_))[tid];
    int c0 = tid * 4;
    float k0 = (h0 - mu) * inv * gn_g[c0 + 0] + gn_b[c0 + 0] + xv.x;
    float k1 = (h1 - mu) * inv * gn_g[c0 + 1] + gn_b[c0 + 1] + xv.y;
    float k2 = (h2 - mu) * inv * gn_g[c0 + 2] + gn_b[c0 + 2] + xv.z;
    float k3 = (h3 - mu) * inv * gn_g[c0 + 3] + gn_b[c0 + 3] + xv.w;
    ((float4*)(hskip + (size_t)row * D_))[tid] = make_float4(k0, k1, k2, k3);
    float t1 = k0 + k1 + k2 + k3;
    float t2 = k0 * k0 + k1 * k1 + k2 * k2 + k3 * k3;
#pragma unroll
    for (int o = 32; o >= 1; o >>= 1) { t1 += __shfl_xor(t1, o); t2 += __shfl_xor(t2, o); }
    __syncthreads();
    if (lane == 0) { red[wv] = t1; red[4 + wv] = t2; }
    __syncthreads();
    t1 = red[0] + red[1] + red[2] + red[3];
    t2 = red[4] + red[5] + red[6] + red[7];
    float mu2 = t1 * (1.f / D_);
    float var2 = t2 * (1.f / D_) - mu2 * mu2;
    float inv2 = rsqrtf(var2 + 1e-5f);
    ushort4 o4;
    o4.x = f2bf((k0 - mu2) * inv2 * ln_g[c0 + 0] + ln_b[c0 + 0]);
    o4.y = f2bf((k1 - mu2) * inv2 * ln_g[c0 + 1] + ln_b[c0 + 1]);
    o4.z = f2bf((k2 - mu2) * inv2 * ln_g[c0 + 2] + ln_b[c0 + 2]);
    o4.w = f2bf((k3 - mu2) * inv2 * ln_g[c0 + 3] + ln_b[c0 + 3]);
    ((ushort4*)(hn + (size_t)row * D_))[tid] = o4;
}

// ---------------------------------------------------------------- GLU pointwise
__global__ void glu_kernel(const u16* __restrict__ zlr, u16* __restrict__ glu) {
    int row = blockIdx.x;
    for (int n = threadIdx.x; n < DFFP; n += 256) {
        float g = 0.f;
        if (n < DFF_) {
            float zl = bf2f(zlr[(size_t)row * NLR + n]);
            float zr = bf2f(zlr[(size_t)row * NLR + DFFP + n]);
            float ge = 0.5f * zr * (1.f + erff(zr * 0.70710678118654752f));
            g = zl * ge;
        }
        glu[(size_t)row * DFFP + n] = f2bf(g);
    }
}

// ---------------------------------------------------------------- launcher
extern "C" void kernel_launch(void* const* d_in, const int* in_sizes, int n_in,
                              void* d_out, int out_size, void* d_ws, size_t ws_size,
                              hipStream_t stream) {
    const float* x      = (const float*)d_in[0];
    const float* Wz     = (const float*)d_in[1];
    const float* Wi     = (const float*)d_in[2];
    const float* Wf     = (const float*)d_in[3];
    const float* Wo     = (const float*)d_in[4];
    const float* bz     = (const float*)d_in[5];
    const float* bi     = (const float*)d_in[6];
    const float* bfb    = (const float*)d_in[7];
    const float* bo     = (const float*)d_in[8];
    const float* Rz     = (const float*)d_in[9];
    const float* Ri     = (const float*)d_in[10];
    const float* Rf     = (const float*)d_in[11];
    const float* Ro     = (const float*)d_in[12];
    const float* conv_w = (const float*)d_in[13];
    const float* conv_b = (const float*)d_in[14];
    const float* ln_g   = (const float*)d_in[15];
    const float* ln_b   = (const float*)d_in[16];
    const float* gn_g   = (const float*)d_in[17];
    const float* gn_b   = (const float*)d_in[18];
    const float* left_w = (const float*)d_in[19];
    const float* left_b = (const float*)d_in[20];
    const float* right_w= (const float*)d_in[21];
    const float* right_b= (const float*)d_in[22];
    const float* last_w = (const float*)d_in[23];
    const float* last_b = (const float*)d_in[24];

    char* ws = (char*)d_ws;
    u16*  BCH   = (u16*)(ws);                     // [1024][4096] bf16 hi, 8 MB
    u16*  BCL   = (u16*)(ws + 8388608);           // lo, 8 MB
    u16*  BLR   = (u16*)(ws + 16777216);          // [2816][1024] bf16, 5.5 MB
    u16*  BLAST = (u16*)(ws + 22544384);          // [1024][1408] bf16, 2.75 MB
    u16*  XN    = (u16*)(ws + 25427968);          // [8192][1024] bf16, 16 MB
    float* XIF32= (float*)(ws + 42205184);        // [8192][1024] fp32, 32 MB
    float* WGIF = (float*)(ws + 75759616);        // [8192][1024][2] fp32 (i,f), 64 MB
    u16*  WGZO  = (u16*)(ws + 142868480);         // [8192][1024][2] bf16 (z,o), 32 MB -> 176,422,912
    // time-disjoint aliases:
    u16*  HSEQ  = (u16*)(ws);                     // over BCH+BCL (dead after conv GEMM)
    float* HSKIP= (float*)(ws + 42205184);        // over XIF32 (dead after proj2)
    u16*  HN    = (u16*)(ws + 25427968);          // over XN (dead after proj2)
    u16*  ZLR   = (u16*)(ws + 75759616);          // over WGIF (dead after scan), 46.1 MB
    u16*  GLU   = (u16*)(ws + 142868480);         // over WGZO (dead after scan), 23.1 MB

    float* out = (float*)d_out;
    float* st_out = out + (size_t)B_ * T_ * D_;

    const int M = B_ * T_;

    ln_x_kernel<<<M, 256, 0, stream>>>(x, ln_g, ln_b, XN);
    build_bconv2<<<16384, 256, 0, stream>>>(conv_w, BCH, BCL);
    build_blr<<<11264, 256, 0, stream>>>(left_w, right_w, BLR);
    build_blast<<<1024, 256, 0, stream>>>(last_w, BLAST);

    // conv as MFMA GEMM, K=4096 tap-major, B hi/lo, fused bias+swish -> XIF32
    gemm_k<0><<<dim3(8, 64), 256, 0, stream>>>(XN, BCH, BCL, 4096, D_, conv_b, nullptr,
                                               nullptr, nullptr, XIF32);
    proj2_kernel<<<dim3(256, 8), 256, 0, stream>>>(XN, XIF32, Wz, Wi, Wf, Wo,
                                                   bz, bi, bfb, bo, WGIF, WGZO);
    scan3_kernel<<<8, 512, 0, stream>>>(WGIF, WGZO, Rz, Ri, Rf, Ro, HSEQ, st_out);
    post_kernel<<<M, 256, 0, stream>>>(HSEQ, x, gn_g, gn_b, ln_g, ln_b, HSKIP, HN);
    gemm_k<2><<<dim3(22, 64), 256, 0, stream>>>(HN, BLR, nullptr, 1024, 1024,
                                                left_b, right_b, nullptr, ZLR, nullptr);
    glu_kernel<<<M, 256, 0, stream>>>(ZLR, GLU);
    gemm_k<3><<<dim3(8, 64), 256, 0, stream>>>(GLU, BLAST, nullptr, DFFP, DFFP,
                                               last_b, nullptr, HSKIP, nullptr, out);
}

// Round 6
// 2709.611 us; speedup vs baseline: 1.7496x; 1.4888x over previous
//
#include <hip/hip_runtime.h>

typedef unsigned short u16;
typedef unsigned int u32;
typedef __attribute__((ext_vector_type(8))) short short8;
typedef __attribute__((ext_vector_type(4))) float f32x4;

#define B_  4
#define T_  2048
#define D_  1024
#define H_  8
#define DH_ 128
#define DFF_ 1365
#define DFFP 1408     // padded DFF (1408 = 11*128)
#define NLR 2816      // 2*DFFP

__device__ __forceinline__ u16 f2bf(float f) {
    u32 u = __float_as_uint(f);
    u32 r = (u + 0x7fffu + ((u >> 16) & 1u)) >> 16;
    return (u16)r;
}
__device__ __forceinline__ float bf2f(u16 v) {
    return __uint_as_float(((u32)v) << 16);
}
__device__ __forceinline__ float frcp(float x) { return __builtin_amdgcn_rcpf(x); }

// ---------------------------------------------------------------- LN over x
__global__ void ln_x_kernel(const float* __restrict__ x, const float* __restrict__ g,
                            const float* __restrict__ b, u16* __restrict__ xn) {
    int row = blockIdx.x, tid = threadIdx.x;
    int lane = tid & 63, wv = tid >> 6;
    __shared__ float red[8];
    float4 v = ((const float4*)(x + (size_t)row * D_))[tid];
    float s = v.x + v.y + v.z + v.w;
    float s2 = v.x * v.x + v.y * v.y + v.z * v.z + v.w * v.w;
#pragma unroll
    for (int o = 32; o >= 1; o >>= 1) { s += __shfl_xor(s, o); s2 += __shfl_xor(s2, o); }
    if (lane == 0) { red[wv] = s; red[4 + wv] = s2; }
    __syncthreads();
    s = red[0] + red[1] + red[2] + red[3];
    s2 = red[4] + red[5] + red[6] + red[7];
    float mu = s * (1.f / D_);
    float var = s2 * (1.f / D_) - mu * mu;
    float inv = rsqrtf(var + 1e-5f);
    int c0 = tid * 4;
    ushort4 o4;
    o4.x = f2bf((v.x - mu) * inv * g[c0 + 0] + b[c0 + 0]);
    o4.y = f2bf((v.y - mu) * inv * g[c0 + 1] + b[c0 + 1]);
    o4.z = f2bf((v.z - mu) * inv * g[c0 + 2] + b[c0 + 2]);
    o4.w = f2bf((v.w - mu) * inv * g[c0 + 3] + b[c0 + 3]);
    ((ushort4*)(xn + (size_t)row * D_))[tid] = o4;
}

// -------------------------------------- conv weight repack, hi/lo bf16 split
__global__ void build_bconv2(const float* __restrict__ cw, u16* __restrict__ oh,
                             u16* __restrict__ ol) {
    int i = blockIdx.x * 256 + threadIdx.x;      // over 1024*4096
    int din = i & 1023, kt = (i >> 10) & 3, dout = i >> 12;
    float v = cw[((size_t)dout * D_ + din) * 4 + kt];
    u16 hi = f2bf(v);
    oh[i] = hi;
    ol[i] = f2bf(v - bf2f(hi));
}

// ----------------------------------------- fp32 block-diag gate projections
__global__ __launch_bounds__(256) void proj2_kernel(
    const u16* __restrict__ xn, const float* __restrict__ xif,
    const float* __restrict__ Wz, const float* __restrict__ Wi,
    const float* __restrict__ Wf, const float* __restrict__ Wo,
    const float* __restrict__ bz, const float* __restrict__ bi,
    const float* __restrict__ bfv, const float* __restrict__ bo,
    float* __restrict__ wgif, u16* __restrict__ wgzo) {
    const int m0 = blockIdx.x * 32;
    const int hd = blockIdx.y;
    const int tid = threadIdx.x;
    const int e = tid & 127, half = tid >> 7;
    __shared__ float xns[32][128];
    __shared__ float xfs[32][128];
    for (int s = tid; s < 32 * 128; s += 256) {
        int r = s >> 7, d = s & 127;
        xns[r][d] = bf2f(xn[(size_t)(m0 + r) * D_ + hd * DH_ + d]);
        xfs[r][d] = xif[(size_t)(m0 + r) * D_ + hd * DH_ + d];
    }
    __syncthreads();
    const float* WA = half ? Wo : Wz;
    const float* WB = half ? Wf : Wi;
    float accA[32], accB[32];
#pragma unroll
    for (int r = 0; r < 32; ++r) { accA[r] = 0.f; accB[r] = 0.f; }
    for (int d = 0; d < 128; ++d) {
        float wa = WA[((size_t)hd * DH_ + d) * DH_ + e];
        float wb = WB[((size_t)hd * DH_ + d) * DH_ + e];
#pragma unroll
        for (int r = 0; r < 32; ++r) {
            accA[r] += xns[r][d] * wa;
            accB[r] += xfs[r][d] * wb;
        }
    }
    float ba = half ? bo[hd * DH_ + e] : bz[hd * DH_ + e];
    float bb = half ? bfv[hd * DH_ + e] : bi[hd * DH_ + e];
#pragma unroll
    for (int r = 0; r < 32; ++r) {
        size_t base = ((size_t)(m0 + r) * D_ + hd * DH_ + e) * 2;
        wgif[base + half] = accB[r] + bb;
        wgzo[base + half] = f2bf(accA[r] + ba);
    }
}

// ------------------------------------------------- MLP weight repack (bf16)
__global__ void build_blr(const float* __restrict__ lw, const float* __restrict__ rw,
                          u16* __restrict__ o) {
    int i = blockIdx.x * 256 + threadIdx.x;      // over 2816*1024
    int k = i & 1023, n = i >> 10;
    float v = 0.f;
    if (n < DFF_) v = lw[(size_t)n * D_ + k];
    else if (n >= DFFP && n < DFFP + DFF_) v = rw[(size_t)(n - DFFP) * D_ + k];
    o[i] = f2bf(v);
}
__global__ void build_blast(const float* __restrict__ lw, u16* __restrict__ o) {
    int n = blockIdx.x;                          // 1024 rows
    for (int k = threadIdx.x; k < DFFP; k += 256) {
        float v = (k < DFF_) ? lw[(size_t)n * DFF_ + k] : 0.f;
        o[(size_t)n * DFFP + k] = f2bf(v);
    }
}

// ---------------------------------------------------------------- GEMM
// MODE 0=CONV (virtual tap-major K=4096, B hi/lo, ->swish-> fp32 XIF)
// MODE 2=LR(->ZLR bf16) 3=LAST(->fp32 out + bias + skip)
template <int MODE>
__global__ __launch_bounds__(256) void gemm_k(
    const u16* __restrict__ A, const u16* __restrict__ Bg, const u16* __restrict__ Bg2,
    int K, int lda,
    const float* __restrict__ bias0, const float* __restrict__ bias1,
    const float* __restrict__ add0, u16* __restrict__ o16, float* __restrict__ o32) {
    const int tid = threadIdx.x;
    const int m0 = blockIdx.y * 128;
    const int n0 = blockIdx.x * 128;
    __shared__ u16 As[128][72];
    __shared__ u16 Bs[128][72];
    __shared__ u16 Bs2[(MODE == 0) ? 128 : 1][72];

    f32x4 zero4 = {0.f, 0.f, 0.f, 0.f};
    f32x4 acc[4][4];
#pragma unroll
    for (int i = 0; i < 4; ++i)
#pragma unroll
        for (int j = 0; j < 4; ++j) acc[i][j] = zero4;

    const int lane = tid & 63, wv = tid >> 6;
    const int wr = (wv >> 1) * 64, wc = (wv & 1) * 64;
    const int fr = lane & 15, kg = (lane >> 4) * 8;

    for (int kb = 0; kb < K; kb += 64) {
#pragma unroll
        for (int it = 0; it < 4; ++it) {
            int slot = tid + it * 256;
            int r = slot >> 3, ch = slot & 7;
            uint4 va;
            if constexpr (MODE == 0) {
                int kk = kb + ch * 8;
                int ktap = kk >> 10, din = kk & 1023;
                int m = m0 + r;
                int t = m & (T_ - 1);
                if (t + ktap - 3 >= 0)
                    va = *(const uint4*)(A + (size_t)(m + ktap - 3) * D_ + din);
                else
                    va = make_uint4(0u, 0u, 0u, 0u);
            } else {
                va = *(const uint4*)(A + (size_t)(m0 + r) * lda + kb + ch * 8);
            }
            *(uint4*)(&As[r][ch * 8]) = va;
            uint4 vb = *(const uint4*)(Bg + (size_t)(n0 + r) * K + kb + ch * 8);
            *(uint4*)(&Bs[r][ch * 8]) = vb;
            if constexpr (MODE == 0) {
                uint4 vc = *(const uint4*)(Bg2 + (size_t)(n0 + r) * K + kb + ch * 8);
                *(uint4*)(&Bs2[r][ch * 8]) = vc;
            }
        }
        __syncthreads();
#pragma unroll
        for (int kt = 0; kt < 2; ++kt) {
            short8 af[4], bfr[4];
#pragma unroll
            for (int i = 0; i < 4; ++i)
                af[i] = *(const short8*)(&As[wr + i * 16 + fr][kt * 32 + kg]);
#pragma unroll
            for (int i = 0; i < 4; ++i)
                bfr[i] = *(const short8*)(&Bs[wc + i * 16 + fr][kt * 32 + kg]);
#pragma unroll
            for (int mi = 0; mi < 4; ++mi)
#pragma unroll
                for (int ni = 0; ni < 4; ++ni)
                    acc[mi][ni] = __builtin_amdgcn_mfma_f32_16x16x32_bf16(
                        af[mi], bfr[ni], acc[mi][ni], 0, 0, 0);
            if constexpr (MODE == 0) {
                short8 bl[4];
#pragma unroll
                for (int i = 0; i < 4; ++i)
                    bl[i] = *(const short8*)(&Bs2[wc + i * 16 + fr][kt * 32 + kg]);
#pragma unroll
                for (int mi = 0; mi < 4; ++mi)
#pragma unroll
                    for (int ni = 0; ni < 4; ++ni)
                        acc[mi][ni] = __builtin_amdgcn_mfma_f32_16x16x32_bf16(
                            af[mi], bl[ni], acc[mi][ni], 0, 0, 0);
            }
        }
        __syncthreads();
    }
#pragma unroll
    for (int mi = 0; mi < 4; ++mi) {
#pragma unroll
        for (int ni = 0; ni < 4; ++ni) {
#pragma unroll
            for (int r = 0; r < 4; ++r) {
                int row = m0 + wr + mi * 16 + (lane >> 4) * 4 + r;
                int col = n0 + wc + ni * 16 + fr;
                float v = acc[mi][ni][r];
                if constexpr (MODE == 0) {
                    float s = v + bias0[col];
                    float sw = s * frcp(1.f + __expf(-s));
                    o32[(size_t)row * D_ + col] = sw;
                } else if constexpr (MODE == 2) {
                    float bv = 0.f;
                    if (col < DFF_) bv = bias0[col];
                    else if (col >= DFFP && col < DFFP + DFF_) bv = bias1[col - DFFP];
                    o16[(size_t)row * NLR + col] = f2bf(v + bv);
                } else {
                    float r0 = v + bias0[col] + add0[(size_t)row * D_ + col];
                    o32[(size_t)row * D_ + col] = r0;
                }
            }
        }
    }
}

// ---------------------------------------------------------------- scan (v4)
// Wave wv owns dq slice [wv*16,(wv+1)*16), all 4 gates (4 acc sets).
// h stored PRE-FRAGMENTED: hf[parity][kt][lane][8] u16, lane-linear 16B ->
// conflict-free ds_read_b128; only lanes with (lane&15)<4 read (real rows),
// others use zero regs. Pointwise: all 64 lanes, atom (b=lane>>4, dq=wv*16+lc)
// via in-wave zl round-trip (no barrier). One s_barrier/step (lgkm only).
// Chains: z,o = h_hi*R_hi (4 each); i,f = h_hi*R_hi + h_lo*R_hi + h_hi*R_lo
// (12 each) -> 32 MFMA/wave/step. i,f math identical to validated R5 kernel.
__global__ __launch_bounds__(512) void scan4_kernel(
    const float* __restrict__ wgif, const u16* __restrict__ wgzo,
    const float* __restrict__ Rz, const float* __restrict__ Ri,
    const float* __restrict__ Rf, const float* __restrict__ Ro,
    u16* __restrict__ hseq, float* __restrict__ st_out) {
    const int head = blockIdx.x;
    const int tid = threadIdx.x;
    const int lane = tid & 63, wv = tid >> 6;
    const int lc = lane & 15, lg = lane >> 4;

    __shared__ u16 hfH[2][4][64][8];     // 8 KB  [parity][kt][laneSlot][j]
    __shared__ u16 hfL[2][4][64][8];     // 8 KB
    __shared__ float zl[8][4][16][4];    // 8 KB  [wave][gate][c][b]

    for (int i = tid; i < 2 * 4 * 64 * 8; i += 512) {
        ((u16*)hfH)[i] = 0;
        ((u16*)hfL)[i] = 0;
    }

    // R fragments (B operand): bfh all 4 gates; bfl only i(g1),f(g2)
    short8 bfh[4][4];
    short8 bfl[2][4];
    {
        const float* Rp[4] = {Rz, Ri, Rf, Ro};
        const int e = wv * 16 + lc;
#pragma unroll
        for (int g = 0; g < 4; ++g) {
            const float* R = Rp[g] + (size_t)head * DH_ * DH_;
#pragma unroll
            for (int kt = 0; kt < 4; ++kt) {
                short8 vh, vl;
#pragma unroll
                for (int j = 0; j < 8; ++j) {
                    int k = kt * 32 + lg * 8 + j;
                    float rv = R[(size_t)k * DH_ + e];
                    u16 hi = f2bf(rv);
                    vh[j] = (short)hi;
                    vl[j] = (short)f2bf(rv - bf2f(hi));
                }
                bfh[g][kt] = vh;
                if (g == 1) bfl[0][kt] = vl;
                if (g == 2) bfl[1][kt] = vl;
            }
        }
    }

    // pointwise atom: batch ab, feature adq
    const int ab = lg;
    const int adq = wv * 16 + lc;
    const float* pifp = wgif + (((size_t)ab * T_) * D_ + head * DH_ + adq) * 2;
    const u16*  pzop = wgzo + (((size_t)ab * T_) * D_ + head * DH_ + adq) * 2;
    u16* hsp = hseq + ((size_t)ab * T_) * D_ + head * DH_ + adq;
    // h-fragment scatter position (u16 index within one parity block of 2048)
    const int fpos = (((adq >> 5) * 64) + (((adq >> 3) & 3) * 16) + ab) * 8 + (adq & 7);
    const bool ard = (lc < 4);   // this lane reads real fragment rows

    float c_s = 0.f, n_s = 0.f, m_s = 0.f, h_s = 0.f;
    float2 pif = *(const float2*)pifp; pifp += 2 * D_;
    u32 pzo = *(const u32*)pzop; pzop += 2 * D_;

    const short8 zero8 = {0, 0, 0, 0, 0, 0, 0, 0};
    __syncthreads();

    for (int t = 0; t < T_; ++t) {
        const int p = t & 1, q = p ^ 1;
        short8 ah[4], al[4];
#pragma unroll
        for (int kt = 0; kt < 4; ++kt) {
            ah[kt] = ard ? *(const short8*)(&hfH[p][kt][lane][0]) : zero8;
            al[kt] = ard ? *(const short8*)(&hfL[p][kt][lane][0]) : zero8;
        }
        f32x4 az = {0.f, 0.f, 0.f, 0.f}, ai = az, af2 = az, ao = az;
#pragma unroll
        for (int kt = 0; kt < 4; ++kt) {
            az  = __builtin_amdgcn_mfma_f32_16x16x32_bf16(ah[kt], bfh[0][kt], az, 0, 0, 0);
            ao  = __builtin_amdgcn_mfma_f32_16x16x32_bf16(ah[kt], bfh[3][kt], ao, 0, 0, 0);
            ai  = __builtin_amdgcn_mfma_f32_16x16x32_bf16(ah[kt], bfh[1][kt], ai, 0, 0, 0);
            af2 = __builtin_amdgcn_mfma_f32_16x16x32_bf16(ah[kt], bfh[2][kt], af2, 0, 0, 0);
        }
#pragma unroll
        for (int kt = 0; kt < 4; ++kt) {
            ai  = __builtin_amdgcn_mfma_f32_16x16x32_bf16(al[kt], bfh[1][kt], ai, 0, 0, 0);
            af2 = __builtin_amdgcn_mfma_f32_16x16x32_bf16(al[kt], bfh[2][kt], af2, 0, 0, 0);
        }
#pragma unroll
        for (int kt = 0; kt < 4; ++kt) {
            ai  = __builtin_amdgcn_mfma_f32_16x16x32_bf16(ah[kt], bfl[0][kt], ai, 0, 0, 0);
            af2 = __builtin_amdgcn_mfma_f32_16x16x32_bf16(ah[kt], bfl[1][kt], af2, 0, 0, 0);
        }
        if (lane < 16) {   // C/D rows 0-3 live in regs 0-3 of lanes 0-15
            *(f32x4*)(&zl[wv][0][lc][0]) = az;
            *(f32x4*)(&zl[wv][1][lc][0]) = ai;
            *(f32x4*)(&zl[wv][2][lc][0]) = af2;
            *(f32x4*)(&zl[wv][3][lc][0]) = ao;
        }
        __builtin_amdgcn_sched_barrier(0);
        // in-wave RAW through LDS (per-wave DS ordering; compiler inserts lgkmcnt)
        float gz = zl[wv][0][lc][ab];
        float gi = zl[wv][1][lc][ab];
        float gf = zl[wv][2][lc][ab];
        float go = zl[wv][3][lc][ab];
        float vz = bf2f((u16)(pzo & 0xffffu)) + gz;
        float vi = pif.x + gi;
        float vf = pif.y + gf;
        float vo = bf2f((u16)(pzo >> 16)) + go;
        if (t < T_ - 1) {   // prefetch next step's gate inputs
            pif = *(const float2*)pifp; pifp += 2 * D_;
            pzo = *(const u32*)pzop; pzop += 2 * D_;
        }
        float z = 1.f - 2.f * frcp(__expf(2.f * vz) + 1.f);   // tanh
        float o = frcp(1.f + __expf(-vo));                    // sigmoid
        float mn = fmaxf(vf + m_s, vi);
        float ii = __expf(vi - mn);
        float ff = __expf(vf + m_s - mn);
        c_s = ff * c_s + ii * z;
        n_s = ff * n_s + ii;
        m_s = mn;
        h_s = o * c_s * frcp(fmaxf(fabsf(n_s), 1e-8f));
        u16 hb = f2bf(h_s);
        ((u16*)hfH)[q * 2048 + fpos] = hb;
        ((u16*)hfL)[q * 2048 + fpos] = f2bf(h_s - bf2f(hb));
        *hsp = hb; hsp += D_;
        asm volatile("s_waitcnt lgkmcnt(0)\n\ts_barrier" ::: "memory");
    }

    int pos = ab * D_ + head * DH_ + adq;
    st_out[pos] = h_s;
    st_out[4096 + pos] = c_s;
    st_out[8192 + pos] = n_s;
    st_out[12288 + pos] = m_s;
}

// --------------------------------------------- GN + skip + LN (post) per row
__global__ void post_kernel(const u16* __restrict__ hseq, const float* __restrict__ x,
                            const float* __restrict__ gn_g, const float* __restrict__ gn_b,
                            const float* __restrict__ ln_g, const float* __restrict__ ln_b,
                            float* __restrict__ hskip, u16* __restrict__ hn) {
    int row = blockIdx.x, tid = threadIdx.x;
    int lane = tid & 63, wv = tid >> 6;
    __shared__ float red[8];
    ushort4 hv = ((const ushort4*)(hseq + (size_t)row * D_))[tid];
    float h0 = bf2f(hv.x), h1 = bf2f(hv.y), h2 = bf2f(hv.z), h3 = bf2f(hv.w);
    float s = h0 + h1 + h2 + h3;
    float s2 = h0 * h0 + h1 * h1 + h2 * h2 + h3 * h3;
#pragma unroll
    for (int o = 32; o >= 1; o >>= 1) { s += __shfl_xor(s, o); s2 += __shfl_xor(s2, o); }
    if (lane == 0) { red[wv] = s; red[4 + wv] = s2; }
    __syncthreads();
    s = red[0] + red[1] + red[2] + red[3];
    s2 = red[4] + red[5] + red[6] + red[7];
    float mu = s * (1.f / D_);
    float var = s2 * (1.f / D_) - mu * mu;
    float inv = rsqrtf(var + 1e-5f);
    float4 xv = ((const float4*)(x + (size_t)row * D_))[tid];
    int c0 = tid * 4;
    float k0 = (h0 - mu) * inv * gn_g[c0 + 0] + gn_b[c0 + 0] + xv.x;
    float k1 = (h1 - mu) * inv * gn_g[c0 + 1] + gn_b[c0 + 1] + xv.y;
    float k2 = (h2 - mu) * inv * gn_g[c0 + 2] + gn_b[c0 + 2] + xv.z;
    float k3 = (h3 - mu) * inv * gn_g[c0 + 3] + gn_b[c0 + 3] + xv.w;
    ((float4*)(hskip + (size_t)row * D_))[tid] = make_float4(k0, k1, k2, k3);
    float t1 = k0 + k1 + k2 + k3;
    float t2 = k0 * k0 + k1 * k1 + k2 * k2 + k3 * k3;
#pragma unroll
    for (int o = 32; o >= 1; o >>= 1) { t1 += __shfl_xor(t1, o); t2 += __shfl_xor(t2, o); }
    __syncthreads();
    if (lane == 0) { red[wv] = t1; red[4 + wv] = t2; }
    __syncthreads();
    t1 = red[0] + red[1] + red[2] + red[3];
    t2 = red[4] + red[5] + red[6] + red[7];
    float mu2 = t1 * (1.f / D_);
    float var2 = t2 * (1.f / D_) - mu2 * mu2;
    float inv2 = rsqrtf(var2 + 1e-5f);
    ushort4 o4;
    o4.x = f2bf((k0 - mu2) * inv2 * ln_g[c0 + 0] + ln_b[c0 + 0]);
    o4.y = f2bf((k1 - mu2) * inv2 * ln_g[c0 + 1] + ln_b[c0 + 1]);
    o4.z = f2bf((k2 - mu2) * inv2 * ln_g[c0 + 2] + ln_b[c0 + 2]);
    o4.w = f2bf((k3 - mu2) * inv2 * ln_g[c0 + 3] + ln_b[c0 + 3]);
    ((ushort4*)(hn + (size_t)row * D_))[tid] = o4;
}

// ---------------------------------------------------------------- GLU pointwise
__global__ void glu_kernel(const u16* __restrict__ zlr, u16* __restrict__ glu) {
    int row = blockIdx.x;
    for (int n = threadIdx.x; n < DFFP; n += 256) {
        float g = 0.f;
        if (n < DFF_) {
            float zl = bf2f(zlr[(size_t)row * NLR + n]);
            float zr = bf2f(zlr[(size_t)row * NLR + DFFP + n]);
            float ge = 0.5f * zr * (1.f + erff(zr * 0.70710678118654752f));
            g = zl * ge;
        }
        glu[(size_t)row * DFFP + n] = f2bf(g);
    }
}

// ---------------------------------------------------------------- launcher
extern "C" void kernel_launch(void* const* d_in, const int* in_sizes, int n_in,
                              void* d_out, int out_size, void* d_ws, size_t ws_size,
                              hipStream_t stream) {
    const float* x      = (const float*)d_in[0];
    const float* Wz     = (const float*)d_in[1];
    const float* Wi     = (const float*)d_in[2];
    const float* Wf     = (const float*)d_in[3];
    const float* Wo     = (const float*)d_in[4];
    const float* bz     = (const float*)d_in[5];
    const float* bi     = (const float*)d_in[6];
    const float* bfb    = (const float*)d_in[7];
    const float* bo     = (const float*)d_in[8];
    const float* Rz     = (const float*)d_in[9];
    const float* Ri     = (const float*)d_in[10];
    const float* Rf     = (const float*)d_in[11];
    const float* Ro     = (const float*)d_in[12];
    const float* conv_w = (const float*)d_in[13];
    const float* conv_b = (const float*)d_in[14];
    const float* ln_g   = (const float*)d_in[15];
    const float* ln_b   = (const float*)d_in[16];
    const float* gn_g   = (const float*)d_in[17];
    const float* gn_b   = (const float*)d_in[18];
    const float* left_w = (const float*)d_in[19];
    const float* left_b = (const float*)d_in[20];
    const float* right_w= (const float*)d_in[21];
    const float* right_b= (const float*)d_in[22];
    const float* last_w = (const float*)d_in[23];
    const float* last_b = (const float*)d_in[24];

    char* ws = (char*)d_ws;
    u16*  BCH   = (u16*)(ws);                     // [1024][4096] bf16 hi, 8 MB
    u16*  BCL   = (u16*)(ws + 8388608);           // lo, 8 MB
    u16*  BLR   = (u16*)(ws + 16777216);          // [2816][1024] bf16, 5.5 MB
    u16*  BLAST = (u16*)(ws + 22544384);          // [1024][1408] bf16, 2.75 MB
    u16*  XN    = (u16*)(ws + 25427968);          // [8192][1024] bf16, 16 MB
    float* XIF32= (float*)(ws + 42205184);        // [8192][1024] fp32, 32 MB
    float* WGIF = (float*)(ws + 75759616);        // [8192][1024][2] fp32 (i,f), 64 MB
    u16*  WGZO  = (u16*)(ws + 142868480);         // [8192][1024][2] bf16 (z,o), 32 MB
    // time-disjoint aliases:
    u16*  HSEQ  = (u16*)(ws);                     // over BCH+BCL (dead after conv GEMM)
    float* HSKIP= (float*)(ws + 42205184);        // over XIF32 (dead after proj2)
    u16*  HN    = (u16*)(ws + 25427968);          // over XN (dead after proj2)
    u16*  ZLR   = (u16*)(ws + 75759616);          // over WGIF (dead after scan), 46.1 MB
    u16*  GLU   = (u16*)(ws + 142868480);         // over WGZO (dead after scan), 23.1 MB

    float* out = (float*)d_out;
    float* st_out = out + (size_t)B_ * T_ * D_;

    const int M = B_ * T_;

    ln_x_kernel<<<M, 256, 0, stream>>>(x, ln_g, ln_b, XN);
    build_bconv2<<<16384, 256, 0, stream>>>(conv_w, BCH, BCL);
    build_blr<<<11264, 256, 0, stream>>>(left_w, right_w, BLR);
    build_blast<<<1024, 256, 0, stream>>>(last_w, BLAST);

    // conv as MFMA GEMM, K=4096 tap-major, B hi/lo, fused bias+swish -> XIF32
    gemm_k<0><<<dim3(8, 64), 256, 0, stream>>>(XN, BCH, BCL, 4096, D_, conv_b, nullptr,
                                               nullptr, nullptr, XIF32);
    proj2_kernel<<<dim3(256, 8), 256, 0, stream>>>(XN, XIF32, Wz, Wi, Wf, Wo,
                                                   bz, bi, bfb, bo, WGIF, WGZO);
    scan4_kernel<<<8, 512, 0, stream>>>(WGIF, WGZO, Rz, Ri, Rf, Ro, HSEQ, st_out);
    post_kernel<<<M, 256, 0, stream>>>(HSEQ, x, gn_g, gn_b, ln_g, ln_b, HSKIP, HN);
    gemm_k<2><<<dim3(22, 64), 256, 0, stream>>>(HN, BLR, nullptr, 1024, 1024,
                                                left_b, right_b, nullptr, ZLR, nullptr);
    glu_kernel<<<M, 256, 0, stream>>>(ZLR, GLU);
    gemm_k<3><<<dim3(8, 64), 256, 0, stream>>>(GLU, BLAST, nullptr, DFFP, DFFP,
                                               last_b, nullptr, HSKIP, nullptr, out);
}

// Round 7
// 2580.441 us; speedup vs baseline: 1.8372x; 1.0501x over previous
//
#include <hip/hip_runtime.h>

typedef unsigned short u16;
typedef unsigned int u32;
typedef __attribute__((ext_vector_type(8))) short short8;
typedef __attribute__((ext_vector_type(4))) float f32x4;

#define B_  4
#define T_  2048
#define D_  1024
#define H_  8
#define DH_ 128
#define DFF_ 1365
#define DFFP 1408     // padded DFF (1408 = 11*128)
#define NLR 2816      // 2*DFFP

__device__ __forceinline__ u16 f2bf(float f) {
    u32 u = __float_as_uint(f);
    u32 r = (u + 0x7fffu + ((u >> 16) & 1u)) >> 16;
    return (u16)r;
}
__device__ __forceinline__ float bf2f(u16 v) {
    return __uint_as_float(((u32)v) << 16);
}
__device__ __forceinline__ float frcp(float x) { return __builtin_amdgcn_rcpf(x); }

// ---------------------------------------------------------------- LN over x
__global__ void ln_x_kernel(const float* __restrict__ x, const float* __restrict__ g,
                            const float* __restrict__ b, u16* __restrict__ xn) {
    int row = blockIdx.x, tid = threadIdx.x;
    int lane = tid & 63, wv = tid >> 6;
    __shared__ float red[8];
    float4 v = ((const float4*)(x + (size_t)row * D_))[tid];
    float s = v.x + v.y + v.z + v.w;
    float s2 = v.x * v.x + v.y * v.y + v.z * v.z + v.w * v.w;
#pragma unroll
    for (int o = 32; o >= 1; o >>= 1) { s += __shfl_xor(s, o); s2 += __shfl_xor(s2, o); }
    if (lane == 0) { red[wv] = s; red[4 + wv] = s2; }
    __syncthreads();
    s = red[0] + red[1] + red[2] + red[3];
    s2 = red[4] + red[5] + red[6] + red[7];
    float mu = s * (1.f / D_);
    float var = s2 * (1.f / D_) - mu * mu;
    float inv = rsqrtf(var + 1e-5f);
    int c0 = tid * 4;
    ushort4 o4;
    o4.x = f2bf((v.x - mu) * inv * g[c0 + 0] + b[c0 + 0]);
    o4.y = f2bf((v.y - mu) * inv * g[c0 + 1] + b[c0 + 1]);
    o4.z = f2bf((v.z - mu) * inv * g[c0 + 2] + b[c0 + 2]);
    o4.w = f2bf((v.w - mu) * inv * g[c0 + 3] + b[c0 + 3]);
    ((ushort4*)(xn + (size_t)row * D_))[tid] = o4;
}

// -------------------------------------- conv weight repack, hi/lo bf16 split
__global__ void build_bconv2(const float* __restrict__ cw, u16* __restrict__ oh,
                             u16* __restrict__ ol) {
    int i = blockIdx.x * 256 + threadIdx.x;      // over 1024*4096
    int din = i & 1023, kt = (i >> 10) & 3, dout = i >> 12;
    float v = cw[((size_t)dout * D_ + din) * 4 + kt];
    u16 hi = f2bf(v);
    oh[i] = hi;
    ol[i] = f2bf(v - bf2f(hi));
}

// ----------------------------------------- fp32 block-diag gate projections
__global__ __launch_bounds__(256) void proj2_kernel(
    const u16* __restrict__ xn, const float* __restrict__ xif,
    const float* __restrict__ Wz, const float* __restrict__ Wi,
    const float* __restrict__ Wf, const float* __restrict__ Wo,
    const float* __restrict__ bz, const float* __restrict__ bi,
    const float* __restrict__ bfv, const float* __restrict__ bo,
    float* __restrict__ wgif, u16* __restrict__ wgzo) {
    const int m0 = blockIdx.x * 32;
    const int hd = blockIdx.y;
    const int tid = threadIdx.x;
    const int e = tid & 127, half = tid >> 7;
    __shared__ float xns[32][128];
    __shared__ float xfs[32][128];
    for (int s = tid; s < 32 * 128; s += 256) {
        int r = s >> 7, d = s & 127;
        xns[r][d] = bf2f(xn[(size_t)(m0 + r) * D_ + hd * DH_ + d]);
        xfs[r][d] = xif[(size_t)(m0 + r) * D_ + hd * DH_ + d];
    }
    __syncthreads();
    const float* WA = half ? Wo : Wz;
    const float* WB = half ? Wf : Wi;
    float accA[32], accB[32];
#pragma unroll
    for (int r = 0; r < 32; ++r) { accA[r] = 0.f; accB[r] = 0.f; }
    for (int d = 0; d < 128; ++d) {
        float wa = WA[((size_t)hd * DH_ + d) * DH_ + e];
        float wb = WB[((size_t)hd * DH_ + d) * DH_ + e];
#pragma unroll
        for (int r = 0; r < 32; ++r) {
            accA[r] += xns[r][d] * wa;
            accB[r] += xfs[r][d] * wb;
        }
    }
    float ba = half ? bo[hd * DH_ + e] : bz[hd * DH_ + e];
    float bb = half ? bfv[hd * DH_ + e] : bi[hd * DH_ + e];
#pragma unroll
    for (int r = 0; r < 32; ++r) {
        size_t base = ((size_t)(m0 + r) * D_ + hd * DH_ + e) * 2;
        wgif[base + half] = accB[r] + bb;
        wgzo[base + half] = f2bf(accA[r] + ba);
    }
}

// ------------------------------------------------- MLP weight repack (bf16)
__global__ void build_blr(const float* __restrict__ lw, const float* __restrict__ rw,
                          u16* __restrict__ o) {
    int i = blockIdx.x * 256 + threadIdx.x;      // over 2816*1024
    int k = i & 1023, n = i >> 10;
    float v = 0.f;
    if (n < DFF_) v = lw[(size_t)n * D_ + k];
    else if (n >= DFFP && n < DFFP + DFF_) v = rw[(size_t)(n - DFFP) * D_ + k];
    o[i] = f2bf(v);
}
__global__ void build_blast(const float* __restrict__ lw, u16* __restrict__ o) {
    int n = blockIdx.x;                          // 1024 rows
    for (int k = threadIdx.x; k < DFFP; k += 256) {
        float v = (k < DFF_) ? lw[(size_t)n * DFF_ + k] : 0.f;
        o[(size_t)n * DFFP + k] = f2bf(v);
    }
}

// ---------------------------------------------------------------- GEMM
// MODE 0=CONV (virtual tap-major K=4096, B hi/lo, ->swish-> fp32 XIF)
// MODE 2=LR(->ZLR bf16) 3=LAST(->fp32 out + bias + skip)
template <int MODE>
__global__ __launch_bounds__(256) void gemm_k(
    const u16* __restrict__ A, const u16* __restrict__ Bg, const u16* __restrict__ Bg2,
    int K, int lda,
    const float* __restrict__ bias0, const float* __restrict__ bias1,
    const float* __restrict__ add0, u16* __restrict__ o16, float* __restrict__ o32) {
    const int tid = threadIdx.x;
    const int m0 = blockIdx.y * 128;
    const int n0 = blockIdx.x * 128;
    __shared__ u16 As[128][72];
    __shared__ u16 Bs[128][72];
    __shared__ u16 Bs2[(MODE == 0) ? 128 : 1][72];

    f32x4 zero4 = {0.f, 0.f, 0.f, 0.f};
    f32x4 acc[4][4];
#pragma unroll
    for (int i = 0; i < 4; ++i)
#pragma unroll
        for (int j = 0; j < 4; ++j) acc[i][j] = zero4;

    const int lane = tid & 63, wv = tid >> 6;
    const int wr = (wv >> 1) * 64, wc = (wv & 1) * 64;
    const int fr = lane & 15, kg = (lane >> 4) * 8;

    for (int kb = 0; kb < K; kb += 64) {
#pragma unroll
        for (int it = 0; it < 4; ++it) {
            int slot = tid + it * 256;
            int r = slot >> 3, ch = slot & 7;
            uint4 va;
            if constexpr (MODE == 0) {
                int kk = kb + ch * 8;
                int ktap = kk >> 10, din = kk & 1023;
                int m = m0 + r;
                int t = m & (T_ - 1);
                if (t + ktap - 3 >= 0)
                    va = *(const uint4*)(A + (size_t)(m + ktap - 3) * D_ + din);
                else
                    va = make_uint4(0u, 0u, 0u, 0u);
            } else {
                va = *(const uint4*)(A + (size_t)(m0 + r) * lda + kb + ch * 8);
            }
            *(uint4*)(&As[r][ch * 8]) = va;
            uint4 vb = *(const uint4*)(Bg + (size_t)(n0 + r) * K + kb + ch * 8);
            *(uint4*)(&Bs[r][ch * 8]) = vb;
            if constexpr (MODE == 0) {
                uint4 vc = *(const uint4*)(Bg2 + (size_t)(n0 + r) * K + kb + ch * 8);
                *(uint4*)(&Bs2[r][ch * 8]) = vc;
            }
        }
        __syncthreads();
#pragma unroll
        for (int kt = 0; kt < 2; ++kt) {
            short8 af[4], bfr[4];
#pragma unroll
            for (int i = 0; i < 4; ++i)
                af[i] = *(const short8*)(&As[wr + i * 16 + fr][kt * 32 + kg]);
#pragma unroll
            for (int i = 0; i < 4; ++i)
                bfr[i] = *(const short8*)(&Bs[wc + i * 16 + fr][kt * 32 + kg]);
#pragma unroll
            for (int mi = 0; mi < 4; ++mi)
#pragma unroll
                for (int ni = 0; ni < 4; ++ni)
                    acc[mi][ni] = __builtin_amdgcn_mfma_f32_16x16x32_bf16(
                        af[mi], bfr[ni], acc[mi][ni], 0, 0, 0);
            if constexpr (MODE == 0) {
                short8 bl[4];
#pragma unroll
                for (int i = 0; i < 4; ++i)
                    bl[i] = *(const short8*)(&Bs2[wc + i * 16 + fr][kt * 32 + kg]);
#pragma unroll
                for (int mi = 0; mi < 4; ++mi)
#pragma unroll
                    for (int ni = 0; ni < 4; ++ni)
                        acc[mi][ni] = __builtin_amdgcn_mfma_f32_16x16x32_bf16(
                            af[mi], bl[ni], acc[mi][ni], 0, 0, 0);
            }
        }
        __syncthreads();
    }
#pragma unroll
    for (int mi = 0; mi < 4; ++mi) {
#pragma unroll
        for (int ni = 0; ni < 4; ++ni) {
#pragma unroll
            for (int r = 0; r < 4; ++r) {
                int row = m0 + wr + mi * 16 + (lane >> 4) * 4 + r;
                int col = n0 + wc + ni * 16 + fr;
                float v = acc[mi][ni][r];
                if constexpr (MODE == 0) {
                    float s = v + bias0[col];
                    float sw = s * frcp(1.f + __expf(-s));
                    o32[(size_t)row * D_ + col] = sw;
                } else if constexpr (MODE == 2) {
                    float bv = 0.f;
                    if (col < DFF_) bv = bias0[col];
                    else if (col >= DFFP && col < DFFP + DFF_) bv = bias1[col - DFFP];
                    o16[(size_t)row * NLR + col] = f2bf(v + bv);
                } else {
                    float r0 = v + bias0[col] + add0[(size_t)row * D_ + col];
                    o32[(size_t)row * D_ + col] = r0;
                }
            }
        }
    }
}

// ---------------------------------------------------------------- scan (v5)
// Row-replication: A-fragment row r = h[batch r&3] (all 16 rows valid) ->
// C/D reg r of EVERY lane = gate value for batch r at its own column ->
// pointwise needs only an in-lane reg select (no zl LDS round-trip at all).
// hf layout [parity][kt][ab*4+lgp][8] u16: reads are 4-way same-address
// broadcast + <=2-way bank alias (free); writes <=2-way. i,f use 3 parallel
// 4-deep MFMA chains (summed after) instead of one 12-deep chain. Gate
// inputs prefetched 2 steps ahead (loop unrolled x2). One s_barrier/step.
__global__ __launch_bounds__(512) void scan5_kernel(
    const float* __restrict__ wgif, const u16* __restrict__ wgzo,
    const float* __restrict__ Rz, const float* __restrict__ Ri,
    const float* __restrict__ Rf, const float* __restrict__ Ro,
    u16* __restrict__ hseq, float* __restrict__ st_out) {
    const int head = blockIdx.x;
    const int tid = threadIdx.x;
    const int lane = tid & 63, wv = tid >> 6;
    const int lc = lane & 15, lg = lane >> 4;

    __shared__ u16 hfH[2][4][16][8];   // [parity][kt][ab*4+lgp][j], 2 KB
    __shared__ u16 hfL[2][4][16][8];   // 2 KB

    for (int i = tid; i < 2 * 4 * 16 * 8; i += 512) {
        ((u16*)hfH)[i] = 0;
        ((u16*)hfL)[i] = 0;
    }

    // R fragments (B operand): bfh all 4 gates; bfl only i(g1),f(g2)
    short8 bfh[4][4];
    short8 bfl[2][4];
    {
        const float* Rp[4] = {Rz, Ri, Rf, Ro};
        const int e = wv * 16 + lc;
#pragma unroll
        for (int g = 0; g < 4; ++g) {
            const float* R = Rp[g] + (size_t)head * DH_ * DH_;
#pragma unroll
            for (int kt = 0; kt < 4; ++kt) {
                short8 vh, vl;
#pragma unroll
                for (int j = 0; j < 8; ++j) {
                    int k = kt * 32 + lg * 8 + j;
                    float rv = R[(size_t)k * DH_ + e];
                    u16 hi = f2bf(rv);
                    vh[j] = (short)hi;
                    vl[j] = (short)f2bf(rv - bf2f(hi));
                }
                bfh[g][kt] = vh;
                if (g == 1) bfl[0][kt] = vl;
                if (g == 2) bfl[1][kt] = vl;
            }
        }
    }

    // pointwise atom: batch ab, feature adq
    const int ab = lg;
    const int adq = wv * 16 + lc;
    const float* pifp = wgif + (((size_t)ab * T_) * D_ + head * DH_ + adq) * 2;
    const u16*  pzop = wgzo + (((size_t)ab * T_) * D_ + head * DH_ + adq) * 2;
    u16* hsp = hseq + ((size_t)ab * T_) * D_ + head * DH_ + adq;
    // write slot (u16 index within one 512-entry parity block)
    const int wpos = ((adq >> 5) * 16 + (ab * 4 + ((adq >> 3) & 3))) * 8 + (adq & 7);
    // read base: fragment row (lane&15) -> batch (lc&3), k-group lg
    const int rbase = ((lc & 3) * 4 + lg) * 8;

    float c_s = 0.f, n_s = 0.f, m_s = 0.f, h_s = 0.f;
    // 2-deep gate-input pipeline
    float2 pif0 = *(const float2*)pifp;
    u32 pzo0 = *(const u32*)pzop;
    float2 pif1 = *(const float2*)(pifp + 2 * D_);
    u32 pzo1 = *(const u32*)(pzop + 2 * D_);

    __syncthreads();

    for (int t = 0; t < T_; t += 2) {
#pragma unroll
        for (int half = 0; half < 2; ++half) {
            const int p = half, q = half ^ 1;
            const int tc = t + half;
            float2 cif = half ? pif1 : pif0;
            u32 czo = half ? pzo1 : pzo0;
            // issue prefetch for tc+2 (2-step latency budget)
            if (tc + 2 < T_) {
                const float2* fi = (const float2*)(pifp + (size_t)(tc + 2) * 2 * D_);
                const u32* fz = (const u32*)(pzop + (size_t)(tc + 2) * 2 * D_);
                if (half) { pif1 = *fi; pzo1 = *fz; }
                else      { pif0 = *fi; pzo0 = *fz; }
            }
            short8 ah[4], al[4];
#pragma unroll
            for (int kt = 0; kt < 4; ++kt) {
                ah[kt] = *(const short8*)(&((u16*)hfH)[p * 512 + kt * 128 + rbase]);
                al[kt] = *(const short8*)(&((u16*)hfL)[p * 512 + kt * 128 + rbase]);
            }
            f32x4 zz = {0.f, 0.f, 0.f, 0.f};
            f32x4 oo = zz, i1 = zz, i2 = zz, i3 = zz, f1 = zz, ff2 = zz, f3 = zz;
#pragma unroll
            for (int kt = 0; kt < 4; ++kt) {
                zz = __builtin_amdgcn_mfma_f32_16x16x32_bf16(ah[kt], bfh[0][kt], zz, 0, 0, 0);
                oo = __builtin_amdgcn_mfma_f32_16x16x32_bf16(ah[kt], bfh[3][kt], oo, 0, 0, 0);
                i1 = __builtin_amdgcn_mfma_f32_16x16x32_bf16(ah[kt], bfh[1][kt], i1, 0, 0, 0);
                f1 = __builtin_amdgcn_mfma_f32_16x16x32_bf16(ah[kt], bfh[2][kt], f1, 0, 0, 0);
                i2 = __builtin_amdgcn_mfma_f32_16x16x32_bf16(al[kt], bfh[1][kt], i2, 0, 0, 0);
                ff2 = __builtin_amdgcn_mfma_f32_16x16x32_bf16(al[kt], bfh[2][kt], ff2, 0, 0, 0);
                i3 = __builtin_amdgcn_mfma_f32_16x16x32_bf16(ah[kt], bfl[0][kt], i3, 0, 0, 0);
                f3 = __builtin_amdgcn_mfma_f32_16x16x32_bf16(ah[kt], bfl[1][kt], f3, 0, 0, 0);
            }
            f32x4 ii4 = (i1 + i2) + i3;
            f32x4 ff4 = (f1 + ff2) + f3;
            // in-lane reg select by lg (compile-time element indices)
            float gz = (lg == 0) ? zz[0] : (lg == 1) ? zz[1] : (lg == 2) ? zz[2] : zz[3];
            float gi = (lg == 0) ? ii4[0] : (lg == 1) ? ii4[1] : (lg == 2) ? ii4[2] : ii4[3];
            float gf = (lg == 0) ? ff4[0] : (lg == 1) ? ff4[1] : (lg == 2) ? ff4[2] : ff4[3];
            float go = (lg == 0) ? oo[0] : (lg == 1) ? oo[1] : (lg == 2) ? oo[2] : oo[3];
            float vz = bf2f((u16)(czo & 0xffffu)) + gz;
            float vi = cif.x + gi;
            float vf = cif.y + gf;
            float vo = bf2f((u16)(czo >> 16)) + go;
            float z = 1.f - 2.f * frcp(__expf(2.f * vz) + 1.f);   // tanh
            float o = frcp(1.f + __expf(-vo));                    // sigmoid
            float mn = fmaxf(vf + m_s, vi);
            float ii = __expf(vi - mn);
            float ff = __expf(vf + m_s - mn);
            c_s = ff * c_s + ii * z;
            n_s = ff * n_s + ii;
            m_s = mn;
            h_s = o * c_s * frcp(fmaxf(fabsf(n_s), 1e-8f));
            u16 hb = f2bf(h_s);
            ((u16*)hfH)[q * 512 + wpos] = hb;
            ((u16*)hfL)[q * 512 + wpos] = f2bf(h_s - bf2f(hb));
            *hsp = hb; hsp += D_;
            asm volatile("s_waitcnt lgkmcnt(0)\n\ts_barrier" ::: "memory");
        }
    }

    int pos = ab * D_ + head * DH_ + adq;
    st_out[pos] = h_s;
    st_out[4096 + pos] = c_s;
    st_out[8192 + pos] = n_s;
    st_out[12288 + pos] = m_s;
}

// --------------------------------------------- GN + skip + LN (post) per row
__global__ void post_kernel(const u16* __restrict__ hseq, const float* __restrict__ x,
                            const float* __restrict__ gn_g, const float* __restrict__ gn_b,
                            const float* __restrict__ ln_g, const float* __restrict__ ln_b,
                            float* __restrict__ hskip, u16* __restrict__ hn) {
    int row = blockIdx.x, tid = threadIdx.x;
    int lane = tid & 63, wv = tid >> 6;
    __shared__ float red[8];
    ushort4 hv = ((const ushort4*)(hseq + (size_t)row * D_))[tid];
    float h0 = bf2f(hv.x), h1 = bf2f(hv.y), h2 = bf2f(hv.z), h3 = bf2f(hv.w);
    float s = h0 + h1 + h2 + h3;
    float s2 = h0 * h0 + h1 * h1 + h2 * h2 + h3 * h3;
#pragma unroll
    for (int o = 32; o >= 1; o >>= 1) { s += __shfl_xor(s, o); s2 += __shfl_xor(s2, o); }
    if (lane == 0) { red[wv] = s; red[4 + wv] = s2; }
    __syncthreads();
    s = red[0] + red[1] + red[2] + red[3];
    s2 = red[4] + red[5] + red[6] + red[7];
    float mu = s * (1.f / D_);
    float var = s2 * (1.f / D_) - mu * mu;
    float inv = rsqrtf(var + 1e-5f);
    float4 xv = ((const float4*)(x + (size_t)row * D_))[tid];
    int c0 = tid * 4;
    float k0 = (h0 - mu) * inv * gn_g[c0 + 0] + gn_b[c0 + 0] + xv.x;
    float k1 = (h1 - mu) * inv * gn_g[c0 + 1] + gn_b[c0 + 1] + xv.y;
    float k2 = (h2 - mu) * inv * gn_g[c0 + 2] + gn_b[c0 + 2] + xv.z;
    float k3 = (h3 - mu) * inv * gn_g[c0 + 3] + gn_b[c0 + 3] + xv.w;
    ((float4*)(hskip + (size_t)row * D_))[tid] = make_float4(k0, k1, k2, k3);
    float t1 = k0 + k1 + k2 + k3;
    float t2 = k0 * k0 + k1 * k1 + k2 * k2 + k3 * k3;
#pragma unroll
    for (int o = 32; o >= 1; o >>= 1) { t1 += __shfl_xor(t1, o); t2 += __shfl_xor(t2, o); }
    __syncthreads();
    if (lane == 0) { red[wv] = t1; red[4 + wv] = t2; }
    __syncthreads();
    t1 = red[0] + red[1] + red[2] + red[3];
    t2 = red[4] + red[5] + red[6] + red[7];
    float mu2 = t1 * (1.f / D_);
    float var2 = t2 * (1.f / D_) - mu2 * mu2;
    float inv2 = rsqrtf(var2 + 1e-5f);
    ushort4 o4;
    o4.x = f2bf((k0 - mu2) * inv2 * ln_g[c0 + 0] + ln_b[c0 + 0]);
    o4.y = f2bf((k1 - mu2) * inv2 * ln_g[c0 + 1] + ln_b[c0 + 1]);
    o4.z = f2bf((k2 - mu2) * inv2 * ln_g[c0 + 2] + ln_b[c0 + 2]);
    o4.w = f2bf((k3 - mu2) * inv2 * ln_g[c0 + 3] + ln_b[c0 + 3]);
    ((ushort4*)(hn + (size_t)row * D_))[tid] = o4;
}

// ---------------------------------------------------------------- GLU pointwise
__global__ void glu_kernel(const u16* __restrict__ zlr, u16* __restrict__ glu) {
    int row = blockIdx.x;
    for (int n = threadIdx.x; n < DFFP; n += 256) {
        float g = 0.f;
        if (n < DFF_) {
            float zl = bf2f(zlr[(size_t)row * NLR + n]);
            float zr = bf2f(zlr[(size_t)row * NLR + DFFP + n]);
            float ge = 0.5f * zr * (1.f + erff(zr * 0.70710678118654752f));
            g = zl * ge;
        }
        glu[(size_t)row * DFFP + n] = f2bf(g);
    }
}

// ---------------------------------------------------------------- launcher
extern "C" void kernel_launch(void* const* d_in, const int* in_sizes, int n_in,
                              void* d_out, int out_size, void* d_ws, size_t ws_size,
                              hipStream_t stream) {
    const float* x      = (const float*)d_in[0];
    const float* Wz     = (const float*)d_in[1];
    const float* Wi     = (const float*)d_in[2];
    const float* Wf     = (const float*)d_in[3];
    const float* Wo     = (const float*)d_in[4];
    const float* bz     = (const float*)d_in[5];
    const float* bi     = (const float*)d_in[6];
    const float* bfb    = (const float*)d_in[7];
    const float* bo     = (const float*)d_in[8];
    const float* Rz     = (const float*)d_in[9];
    const float* Ri     = (const float*)d_in[10];
    const float* Rf     = (const float*)d_in[11];
    const float* Ro     = (const float*)d_in[12];
    const float* conv_w = (const float*)d_in[13];
    const float* conv_b = (const float*)d_in[14];
    const float* ln_g   = (const float*)d_in[15];
    const float* ln_b   = (const float*)d_in[16];
    const float* gn_g   = (const float*)d_in[17];
    const float* gn_b   = (const float*)d_in[18];
    const float* left_w = (const float*)d_in[19];
    const float* left_b = (const float*)d_in[20];
    const float* right_w= (const float*)d_in[21];
    const float* right_b= (const float*)d_in[22];
    const float* last_w = (const float*)d_in[23];
    const float* last_b = (const float*)d_in[24];

    char* ws = (char*)d_ws;
    u16*  BCH   = (u16*)(ws);                     // [1024][4096] bf16 hi, 8 MB
    u16*  BCL   = (u16*)(ws + 8388608);           // lo, 8 MB
    u16*  BLR   = (u16*)(ws + 16777216);          // [2816][1024] bf16, 5.5 MB
    u16*  BLAST = (u16*)(ws + 22544384);          // [1024][1408] bf16, 2.75 MB
    u16*  XN    = (u16*)(ws + 25427968);          // [8192][1024] bf16, 16 MB
    float* XIF32= (float*)(ws + 42205184);        // [8192][1024] fp32, 32 MB
    float* WGIF = (float*)(ws + 75759616);        // [8192][1024][2] fp32 (i,f), 64 MB
    u16*  WGZO  = (u16*)(ws + 142868480);         // [8192][1024][2] bf16 (z,o), 32 MB
    // time-disjoint aliases:
    u16*  HSEQ  = (u16*)(ws);                     // over BCH+BCL (dead after conv GEMM)
    float* HSKIP= (float*)(ws + 42205184);        // over XIF32 (dead after proj2)
    u16*  HN    = (u16*)(ws + 25427968);          // over XN (dead after proj2)
    u16*  ZLR   = (u16*)(ws + 75759616);          // over WGIF (dead after scan), 46.1 MB
    u16*  GLU   = (u16*)(ws + 142868480);         // over WGZO (dead after scan), 23.1 MB

    float* out = (float*)d_out;
    float* st_out = out + (size_t)B_ * T_ * D_;

    const int M = B_ * T_;

    ln_x_kernel<<<M, 256, 0, stream>>>(x, ln_g, ln_b, XN);
    build_bconv2<<<16384, 256, 0, stream>>>(conv_w, BCH, BCL);
    build_blr<<<11264, 256, 0, stream>>>(left_w, right_w, BLR);
    build_blast<<<1024, 256, 0, stream>>>(last_w, BLAST);

    // conv as MFMA GEMM, K=4096 tap-major, B hi/lo, fused bias+swish -> XIF32
    gemm_k<0><<<dim3(8, 64), 256, 0, stream>>>(XN, BCH, BCL, 4096, D_, conv_b, nullptr,
                                               nullptr, nullptr, XIF32);
    proj2_kernel<<<dim3(256, 8), 256, 0, stream>>>(XN, XIF32, Wz, Wi, Wf, Wo,
                                                   bz, bi, bfb, bo, WGIF, WGZO);
    scan5_kernel<<<8, 512, 0, stream>>>(WGIF, WGZO, Rz, Ri, Rf, Ro, HSEQ, st_out);
    post_kernel<<<M, 256, 0, stream>>>(HSEQ, x, gn_g, gn_b, ln_g, ln_b, HSKIP, HN);
    gemm_k<2><<<dim3(22, 64), 256, 0, stream>>>(HN, BLR, nullptr, 1024, 1024,
                                                left_b, right_b, nullptr, ZLR, nullptr);
    glu_kernel<<<M, 256, 0, stream>>>(ZLR, GLU);
    gemm_k<3><<<dim3(8, 64), 256, 0, stream>>>(GLU, BLAST, nullptr, DFFP, DFFP,
                                               last_b, nullptr, HSKIP, nullptr, out);
}